// Round 14
// baseline (264.964 us; speedup 1.0000x reference)
//
#include <hip/hip_runtime.h>
#include <math.h>

// Problem constants: B=2, T=2048, H=8, Dk=64, D=512
#define BB 2
#define TT 2048
#define HH 8
#define DK 64
#define DD 512
#define MM (BB * TT)
#define WSZ (128 * 4096)   // u16 per packed weight

typedef unsigned int u32;
typedef unsigned short u16;
typedef __bf16 bf16x8 __attribute__((ext_vector_type(8)));
typedef float f32x4 __attribute__((ext_vector_type(4)));

union frag_u { bf16x8 f; u16 u[8]; u32 w[4]; };

// fp32 -> bf16 hi + bf16 lo (RNE both); x ~= hi + lo to ~2^-20 rel.
__device__ __forceinline__ void split2(float x, u16& h, u16& l) {
    u32 u = __float_as_uint(x);
    u32 hi = (u + 0x7fffu + ((u >> 16) & 1u)) >> 16;
    float hif = __uint_as_float(hi << 16);
    float lof = x - hif;                       // exact
    u32 ul = __float_as_uint(lof);
    u32 lo = (ul + 0x7fffu + ((ul >> 16) & 1u)) >> 16;
    h = (u16)hi; l = (u16)lo;
}
// fp32 -> bf16 RNE (hi only)
__device__ __forceinline__ u16 bf16_rne(float x) {
    u32 u = __float_as_uint(x);
    return (u16)((u + 0x7fffu + ((u >> 16) & 1u)) >> 16);
}

// ---------------------------------------------------------------------------
// Granule pack helper: 8 fp32 -> hi/lo uint4 pair at granule g of dst tile.
// ---------------------------------------------------------------------------
__device__ __forceinline__ void pack_granule(const float* xs, u16* dt, int g) {
    u32 hw[4], lw[4];
#pragma unroll
    for (int e = 0; e < 4; e++) {
        u16 h0, l0, h1, l1;
        split2(xs[2 * e], h0, l0);
        split2(xs[2 * e + 1], h1, l1);
        hw[e] = (u32)h0 | ((u32)h1 << 16);
        lw[e] = (u32)l0 | ((u32)l1 << 16);
    }
    *(uint4*)(dt + g * 8)        = make_uint4(hw[0], hw[1], hw[2], hw[3]);
    *(uint4*)(dt + 2048 + g * 8) = make_uint4(lw[0], lw[1], lw[2], lw[3]);
}

// ---------------------------------------------------------------------------
// Prepack a GEMM A-operand: fp32 [4096,512] -> 32-row x 64-k hi/lo granule
// tiles. bid: rb = bid>>3 (row-block), kb = bid&7 (k-block).
// ---------------------------------------------------------------------------
__device__ __forceinline__ void prepack_a_body(
    const float* __restrict__ src, u16* __restrict__ dst, int bid, int tid) {
    const int r = tid >> 3, f = tid & 7;
    const float* p = src + ((size_t)(bid >> 3) * 32 + r) * 512
                         + (size_t)(bid & 7) * 64 + f * 8;
    float4 a  = *(const float4*)p;
    float4 b4 = *(const float4*)(p + 4);
    float xs[8] = {a.x, a.y, a.z, a.w, b4.x, b4.y, b4.z, b4.w};
    const int s = f >> 2, kq = f & 3, nt = r >> 4, n = r & 15;
    const int g = nt * 128 + n * 8 + ((4 * s + kq + 5 * n) & 7);
    pack_granule(xs, dst + (size_t)bid * 4096, g);
}

// ---------------------------------------------------------------------------
// R17 FUSED all prepacks (independent work, ONE launch). Grid 4736:
//   bid < 640       : 5 weight matrices -> B-frag granule tiles (LDS transp)
//   640 <= bid <1664: sinusoid pe (fp64, matches numpy) -> packed A tiles
//   bid >= 1664     : Q/K/V A-prepack (reads raw inputs only)
// ---------------------------------------------------------------------------
__global__ __launch_bounds__(256) void prepack_all_kernel(
    const float* __restrict__ W0, const float* __restrict__ W1,
    const float* __restrict__ W2, const float* __restrict__ W3,
    const float* __restrict__ W4, u16* __restrict__ dstW,
    u16* __restrict__ dstPe,
    const float* __restrict__ sq, const float* __restrict__ sk,
    const float* __restrict__ sv, u16* __restrict__ dq,
    u16* __restrict__ dk, u16* __restrict__ dv) {
    __shared__ float tw[64][36];
    const int tid = threadIdx.x;
    if (blockIdx.x < 640) {
        const int bid = blockIdx.x;
        const int widx = bid >> 7, loc = bid & 127;
        const int nb2 = loc >> 3, kb = loc & 7;
        const float* Wsrc = widx == 0 ? W0 : widx == 1 ? W1 : widx == 2 ? W2
                          : widx == 3 ? W3 : W4;
        const int kl = tid >> 2, gr = tid & 3;
        const float* p = Wsrc + (size_t)(kb * 64 + kl) * 512 + nb2 * 32 + gr * 8;
        float4 a  = *(const float4*)p;
        float4 b4 = *(const float4*)(p + 4);
        *(float4*)&tw[kl][gr * 8]     = a;
        *(float4*)&tw[kl][gr * 8 + 4] = b4;
        __syncthreads();
        const int n5 = tid >> 3, f = tid & 7, s = f >> 2, kq = f & 3;
        float xs[8];
#pragma unroll
        for (int e = 0; e < 8; e++) xs[e] = tw[s * 32 + kq * 8 + e][n5];
        const int n = n5 & 15, nt = n5 >> 4;
        const int g = nt * 128 + n * 8 + ((4 * s + kq + 5 * n) & 7);
        pack_granule(xs, dstW + (size_t)bid * 4096, g);
    } else if (blockIdx.x < 1664) {
        const int bid = blockIdx.x - 640;
        const int r = tid >> 3, f = tid & 7;
        const int m  = (bid >> 3) * 32 + r;          // pe row
        const int c0 = (bid & 7) * 64 + f * 8;       // col base
        float xs[8];
#pragma unroll
        for (int e = 0; e < 8; e++) {
            int col = c0 + e;
            int j = col & 255;
            double inv_freq = exp((double)(-2 * j) * (9.210340371976184 / 512.0));
            double ang = (double)(TT - m) * inv_freq;
            xs[e] = (col < 256) ? (float)sin(ang) : (float)cos(ang);
        }
        const int s = f >> 2, kq = f & 3, nt = r >> 4, n = r & 15;
        const int g = nt * 128 + n * 8 + ((4 * s + kq + 5 * n) & 7);
        pack_granule(xs, dstPe + (size_t)bid * 4096, g);
    } else {
        const int bid = blockIdx.x - 1664;
        const int sel = bid >> 10, sub = bid & 1023;
        const float* s = sel == 0 ? sq : sel == 1 ? sk : sv;
        u16* d = sel == 0 ? dq : sel == 1 ? dk : dv;
        prepack_a_body(s, d, sub, tid);
    }
}

// ---------------------------------------------------------------------------
// MFMA GEMM, bf16 hi/lo emulation: C[4096,512] = A @ W + bias via prepacked
// granule tiles. 64x64 tile, BK=64, 4 waves each 32x32.
// C = Ah*Wh + Ah*Wl + Al*Wh. XCD swizzle: bx = nb*64 + mp.
// R19 DIRECT-L2, BARRIER-FREE main loop: the old version was LDS-bound
// (16 ds_read_b128 vs 12 MFMAs per k-step per wave, ~9x oversubscribed per
// CU) with a full vmcnt-drain barrier every k-step at 2 blocks/CU. Both A
// and W fragments are now read straight from the packed global tiles
// (attn-proven pattern). XCD math: bx%8 = mp%8, so all 8 nb-blocks sharing
// an A-panel sit on the SAME XCD -> A panel L2-local, 8x reuse; W slices
// are L2/L1-resident. LDS shrinks to an epilogue-only Cl (17.4 KB, one
// barrier) -> 4+ blocks/CU. Values bit-identical (same frags, same order).
// FUSED EPILOGUES (EPI):
//   EPI 0: plain fp32 C write (out proj)
//   EPI 1: packed K tiles SCALED BY 1/8 + cbk dot (cb . k * 0.125 - 8)
//   EPI 2: packed V tiles (transposed V-frag layout)
//   EPI 3: packed R chunks SCALED BY 1/8 + rbrk dot (rb . relk * 0.125)
//   EPI 4: packed Q as A-granule tiles (Q proj; attn reads frags directly)
// ---------------------------------------------------------------------------
__device__ __forceinline__ void gemm_full(
    const u16* __restrict__ Apk, const u16* __restrict__ Wpk,
    const float* __restrict__ bias, float* __restrict__ C,
    u16* __restrict__ Ppk, const float* __restrict__ dotv,
    float* __restrict__ dotout, int EPI, int bx, int tid) {
    __shared__ float Cl[64][68];                    // epilogue only (17.4 KB)

    const int w = tid >> 6, lane = tid & 63, quad = lane >> 4, c = lane & 15;
    const int mp = bx & 63, nb = bx >> 6;
    const int mq = w >> 1, nq = w & 1;

    // per-wave operand tile bases (global, L2-resident)
    const u16* Abase = Apk + (size_t)((2 * mp + mq) * 8) * 4096;
    const u16* Wbase = Wpk + (size_t)((2 * nb + nq) * 8) * 4096;

    f32x4 acc[2][2];
#pragma unroll
    for (int mh = 0; mh < 2; mh++)
#pragma unroll
        for (int nh = 0; nh < 2; nh++) acc[mh][nh] = (f32x4){0.f, 0.f, 0.f, 0.f};

#pragma unroll
    for (int kb = 0; kb < 8; kb++) {
        const u16* Ab = Abase + (size_t)kb * 4096;
        const u16* Wb = Wbase + (size_t)kb * 4096;
#pragma unroll
        for (int s = 0; s < 2; s++) {
            bf16x8 ah[2], al[2], wh[2], wl[2];
#pragma unroll
            for (int t = 0; t < 2; t++) {
                int g = (t << 7) + (c << 3) + (((s << 2) + quad + 5 * c) & 7);
                ah[t] = *(const bf16x8*)(Ab + g * 8);
                al[t] = *(const bf16x8*)(Ab + 2048 + g * 8);
                wh[t] = *(const bf16x8*)(Wb + g * 8);
                wl[t] = *(const bf16x8*)(Wb + 2048 + g * 8);
            }
            __builtin_amdgcn_s_setprio(1);
#pragma unroll
            for (int mh = 0; mh < 2; mh++)
#pragma unroll
                for (int nh = 0; nh < 2; nh++) {
                    acc[mh][nh] = __builtin_amdgcn_mfma_f32_16x16x32_bf16(
                        ah[mh], wh[nh], acc[mh][nh], 0, 0, 0);
                    acc[mh][nh] = __builtin_amdgcn_mfma_f32_16x16x32_bf16(
                        ah[mh], wl[nh], acc[mh][nh], 0, 0, 0);
                    acc[mh][nh] = __builtin_amdgcn_mfma_f32_16x16x32_bf16(
                        al[mh], wh[nh], acc[mh][nh], 0, 0, 0);
                }
            __builtin_amdgcn_s_setprio(0);
        }
    }

    const int n0 = nb * 64 + nq * 32;
    float bv0 = bias ? bias[n0 + c] : 0.f;
    float bv1 = bias ? bias[n0 + 16 + c] : 0.f;

    if (EPI == 0) {
        const int m0 = mp * 64 + mq * 32;
#pragma unroll
        for (int mh = 0; mh < 2; mh++)
#pragma unroll
            for (int r = 0; r < 4; r++) {
                size_t row = (size_t)(m0 + mh * 16 + quad * 4 + r) * 512;
                C[row + n0 + c]      = acc[mh][0][r] + bv0;
                C[row + n0 + 16 + c] = acc[mh][1][r] + bv1;
            }
        return;
    }

    // ---- packing epilogues: C tile -> LDS fp32, then granule-pack ----
    // Each wave writes its own disjoint 32x32 quadrant; one barrier.
    {
        const int rbase = mq * 32;
#pragma unroll
        for (int mh = 0; mh < 2; mh++)
#pragma unroll
            for (int r = 0; r < 4; r++) {
                int row = rbase + mh * 16 + quad * 4 + r;
                Cl[row][nq * 32 + c]      = acc[mh][0][r] + bv0;
                Cl[row][nq * 32 + 16 + c] = acc[mh][1][r] + bv1;
            }
    }
    __syncthreads();

    if (EPI == 2) {                                // V tiles (transposed frag)
        const int b = mp >> 5, jt0 = (mp & 31) * 2;
        const int d = tid >> 2, kq = tid & 3;
        const int n = d & 15;
        const int g = (d >> 4) * 64 + n * 4 + ((kq + (n >> 1)) & 3);
#pragma unroll
        for (int ht = 0; ht < 2; ht++) {
            float xs[8];
#pragma unroll
            for (int e = 0; e < 8; e++) xs[e] = Cl[ht * 32 + kq * 8 + e][d];
            u16* dt = Ppk + (size_t)(b * 512 + nb * 64 + jt0 + ht) * 4096;
            pack_granule(xs, dt, g);
        }
        return;
    }

    // EPI 1 (K, x1/8) / EPI 3 (R, x1/8) / EPI 4 (Q, raw): B/A-frag granule
    {
        const float scl = (EPI == 4) ? 1.0f : 0.125f;
        const int rr = tid >> 3, f = tid & 7;
        const int s = f >> 2, kq = f & 3, nt = rr >> 4, n = rr & 15;
        const int g = nt * 128 + n * 8 + ((4 * s + kq + 5 * n) & 7);
#pragma unroll
        for (int ht = 0; ht < 2; ht++) {
            float xs[8];
#pragma unroll
            for (int e = 0; e < 8; e++) xs[e] = Cl[ht * 32 + rr][f * 8 + e] * scl;
            size_t tidx = (EPI == 1)
                ? (size_t)((mp >> 5) * 512 + nb * 64 + (mp & 31) * 2 + ht)
                : (EPI == 3)
                ? (size_t)(nb * 128 + mp * 2 + ht)
                : (size_t)((mp * 2 + ht) * 8 + nb);
            pack_granule(xs, Ppk + tidx * 4096, g);
        }
    }
    if (EPI != 4 && tid < 64) {                    // bias-fold dot, 1 row/lane
        const float* dv = dotv + nb * 64;
        const float* rowp = Cl[tid];
        float sacc = 0.f;
#pragma unroll
        for (int d = 0; d < 64; d++) sacc += dv[d] * rowp[d];
        int m = mp * 64 + tid;
        if (EPI == 1) {
            int b = m >> 11, t = m & 2047;
            dotout[((size_t)nb * BB + b) * TT + t] = sacc * 0.125f - 8.0f;
        } else {
            dotout[(size_t)nb * 4096 + m] = sacc * 0.125f;
        }
    }
}

__global__ __launch_bounds__(256, 3) void gemm_mfma_kernel(
    const u16* __restrict__ Apk, const u16* __restrict__ Wpk,
    const float* __restrict__ bias, float* __restrict__ C) {
    gemm_full(Apk, Wpk, bias, C, nullptr, nullptr, nullptr, 0,
              blockIdx.x, threadIdx.x);
}

// rel_k GEMM: pe-packed A x Wr -> packed R chunks (x1/8) + rbrk. Grid 512.
__global__ __launch_bounds__(256, 3) void gemm_relk_kernel(
    const u16* __restrict__ Apk, const u16* __restrict__ Wpk,
    const float* __restrict__ rb, u16* __restrict__ Rpk,
    float* __restrict__ rbrk) {
    gemm_full(Apk, Wpk, nullptr, nullptr, Rpk, rb, rbrk, 3,
              blockIdx.x, threadIdx.x);
}

// Fused Q/K/V projection GEMMs: grid 1536, widx = bx>>9.
// widx0 -> packed Q A-tiles (EPI4); widx1 -> packed K (x1/8) + cbk;
// widx2 -> packed V.
__global__ __launch_bounds__(256, 3) void gemm3_mfma_kernel(
    const u16* __restrict__ Aq, const u16* __restrict__ Ak,
    const u16* __restrict__ Av, const u16* __restrict__ Wpk,
    const float* __restrict__ bq, const float* __restrict__ bk,
    const float* __restrict__ bv, const float* __restrict__ cb,
    u16* __restrict__ Qpk, u16* __restrict__ Kpk, u16* __restrict__ Vpk,
    float* __restrict__ cbk) {
    const int widx = blockIdx.x >> 9, bx = blockIdx.x & 511;
    const u16* A = widx == 0 ? Aq : widx == 1 ? Ak : Av;
    const u16* W = Wpk + (size_t)widx * WSZ;
    const float* bias = widx == 0 ? bq : widx == 1 ? bk : bv;
    u16* P = widx == 0 ? Qpk : widx == 1 ? Kpk : Vpk;
    const int EPI = widx == 0 ? 4 : widx;
    gemm_full(A, W, bias, nullptr, P, widx == 1 ? cb : nullptr,
              widx == 1 ? cbk : nullptr, EPI, bx, threadIdx.x);
}

// ---------------------------------------------------------------------------
// MFMA flash attention with Transformer-XL rel-shift (unchanged from R12,
// the best measured attn @ ~103 us).
// R8-R14: no-max softmax (-8 shift in cbk), l = mfma(p, ones), KV-split
// 2-wave blocks, no in-loop barriers, 3-slot mod-3 ring, per-head XCD-L2
// affinity, 32 q-rows/wave, packed A-tile epilogue, V-load hoist (R17).
// R18a Q-DIRECT: Q fragments straight from packed Q A-tiles; 1/8 scale in
// the K/R packs (bit-identical). R18b HI-ONLY P with the V-hoist cover.
// ---------------------------------------------------------------------------
__global__ __launch_bounds__(128, 2) void attn_mfma_kernel(
    const u16* __restrict__ Qpk, const u16* __restrict__ Kpk,
    const u16* __restrict__ Vpk, const u16* __restrict__ Rpk,
    const float* __restrict__ cbk, const float* __restrict__ rbrk,
    u16* __restrict__ Aout) {
    __shared__ float Ring[2 * 3 * 1120];           // [wave][slot][32][35]
    __shared__ __align__(16) u16 Pbuf[2 * 1280];   // [wave][32 rows][40]

    const int tid = threadIdx.x;
    const int w = tid >> 6, lane = tid & 63, quad = lane >> 4, c = lane & 15;
    const int bx = blockIdx.x;
    const int h = bx & 7, b = (bx >> 3) & 1, it = bx >> 4;   // h in low bits
    const int i0 = it * 32;

    // Q fragments direct from packed A-tile: [rg][s]
    frag_u qh[2][2], ql[2][2];
    {
        const u16* Qt = Qpk + (size_t)((b * 64 + it) * 8 + h) * 4096;
#pragma unroll
        for (int rg = 0; rg < 2; rg++)
#pragma unroll
            for (int s = 0; s < 2; s++) {
                int g = (rg << 7) + (c << 3) + (((s << 2) + quad + 5 * c) & 7);
                qh[rg][s].f = *(const bf16x8*)(Qt + g * 8);
                ql[rg][s].f = *(const bf16x8*)(Qt + 2048 + g * 8);
            }
    }

    // all-ones B fragment for row-sum MFMAs (l accumulation)
    frag_u onesf;
#pragma unroll
    for (int j2 = 0; j2 < 8; j2++) onesf.u[j2] = 0x3f80u;   // bf16 1.0

    const u16* Ktiles  = Kpk + (size_t)(b * HH + h) * 64 * 4096;
    const u16* Vtiles  = Vpk + (size_t)(b * HH + h) * 64 * 4096;
    const u16* Rchunks = Rpk + (size_t)h * 128 * 4096;
    const float* rbrk_h = rbrk + (size_t)h * (2 * TT);
    const float* cbk_h  = cbk + ((size_t)h * BB + b) * TT;

    auto read_kr = [&](const u16* reg, int nt, int s, bf16x8& fh, bf16x8& fl) {
        int g = (nt << 7) + (c << 3) + (((s << 2) + quad + 5 * c) & 7);
        fh = *(const bf16x8*)(reg + g * 8);
        fl = *(const bf16x8*)(reg + 2048 + g * 8);
    };
    auto read_v = [&](const u16* Vb, int ntd, bf16x8& fh, bf16x8& fl) {
        int g = ntd * 64 + c * 4 + ((quad + (c >> 1)) & 3);
        fh = *(const bf16x8*)(Vb + g * 8);
        fl = *(const bf16x8*)(Vb + 2048 + g * 8);
    };

    // produce: Q(32 rows) . (R/8)-chunk -> ring slot [32][35]
    auto produce = [&](int cidx) {
        const u16* Rc = Rchunks + (size_t)cidx * 4096;
        float* ringw = Ring + (w * 3 + cidx % 3) * 1120;
#pragma unroll
        for (int ntp = 0; ntp < 2; ntp++) {
            f32x4 a0 = {0.f, 0.f, 0.f, 0.f};
            f32x4 a1 = {0.f, 0.f, 0.f, 0.f};
#pragma unroll
            for (int s = 0; s < 2; s++) {
                int g = (ntp << 7) + (c << 3) + (((s << 2) + quad + 5 * c) & 7);
                bf16x8 fh = *(const bf16x8*)(Rc + g * 8);
                bf16x8 fl = *(const bf16x8*)(Rc + 2048 + g * 8);
                a0 = __builtin_amdgcn_mfma_f32_16x16x32_bf16(qh[0][s].f, fh, a0, 0, 0, 0);
                a0 = __builtin_amdgcn_mfma_f32_16x16x32_bf16(qh[0][s].f, fl, a0, 0, 0, 0);
                a0 = __builtin_amdgcn_mfma_f32_16x16x32_bf16(ql[0][s].f, fh, a0, 0, 0, 0);
                a1 = __builtin_amdgcn_mfma_f32_16x16x32_bf16(qh[1][s].f, fh, a1, 0, 0, 0);
                a1 = __builtin_amdgcn_mfma_f32_16x16x32_bf16(qh[1][s].f, fl, a1, 0, 0, 0);
                a1 = __builtin_amdgcn_mfma_f32_16x16x32_bf16(ql[1][s].f, fh, a1, 0, 0, 0);
            }
            float rbv = rbrk_h[cidx * 32 + ntp * 16 + c];
            int mpos = ntp * 16 + c;
#pragma unroll
            for (int r = 0; r < 4; r++)
                ringw[(quad * 4 + r) * 35 + mpos] = a0[r] + rbv;
#pragma unroll
            for (int r = 0; r < 4; r++)
                ringw[(16 + quad * 4 + r) * 35 + mpos] = a1[r] + rbv;
        }
    };

    // base m at (row i0, local j=0); aligned to 32 since i0,j0 = 0 mod 32.
    const int base = TT - i0 + 1024 * w;
    const int F = (base >> 5) - 1;      // first chunk of the t=0 window
    produce(F);
    produce(F + 1);

    f32x4 o[2][4];
    f32x4 acc_l[2];
#pragma unroll
    for (int rg = 0; rg < 2; rg++) {
        acc_l[rg] = (f32x4){0.f, 0.f, 0.f, 0.f};
#pragma unroll
        for (int nt = 0; nt < 4; nt++) o[rg][nt] = (f32x4){0.f, 0.f, 0.f, 0.f};
    }

    for (int t = 0; t < 32; t++) {
        const int j0 = 1024 * w + 32 * t;
        const u16* Kb = Ktiles + (size_t)(w * 32 + t) * 4096;
        const u16* Vb = Vtiles + (size_t)(w * 32 + t) * 4096;

        // V loads issued FIRST — consumed at PV (end of body), covered by
        // produce + QK + softmax in between (R17).
        bf16x8 vfh[4], vfl[4];
#pragma unroll
        for (int ntd = 0; ntd < 4; ntd++) read_v(Vb, ntd, vfh[ntd], vfl[ntd]);

        int cnext = F + t + 2;
        if (cnext < 128) produce(cnext);

        // window chunks {F+t, F+t+1}; slots mod 3
        const int slo = (F + t) % 3;
        const int shi = (slo == 2) ? 0 : slo + 1;
        const int off_lo = (w * 3 + slo) * 1120;
        const int off_hi = (w * 3 + shi) * 1120;
        float cbv0 = cbk_h[j0 + c];
        float cbv1 = cbk_h[j0 + 16 + c];
        float sv[2][2][4];
#pragma unroll
        for (int nt = 0; nt < 2; nt++) {
            f32x4 sc0 = {0.f, 0.f, 0.f, 0.f};
            f32x4 sc1 = {0.f, 0.f, 0.f, 0.f};
            bf16x8 fh0, fl0, fh1, fl1;
            read_kr(Kb, nt, 0, fh0, fl0);
            read_kr(Kb, nt, 1, fh1, fl1);
            __builtin_amdgcn_s_setprio(1);
            sc0 = __builtin_amdgcn_mfma_f32_16x16x32_bf16(qh[0][0].f, fh0, sc0, 0, 0, 0);
            sc0 = __builtin_amdgcn_mfma_f32_16x16x32_bf16(qh[0][0].f, fl0, sc0, 0, 0, 0);
            sc0 = __builtin_amdgcn_mfma_f32_16x16x32_bf16(ql[0][0].f, fh0, sc0, 0, 0, 0);
            sc0 = __builtin_amdgcn_mfma_f32_16x16x32_bf16(qh[0][1].f, fh1, sc0, 0, 0, 0);
            sc0 = __builtin_amdgcn_mfma_f32_16x16x32_bf16(qh[0][1].f, fl1, sc0, 0, 0, 0);
            sc0 = __builtin_amdgcn_mfma_f32_16x16x32_bf16(ql[0][1].f, fh1, sc0, 0, 0, 0);
            sc1 = __builtin_amdgcn_mfma_f32_16x16x32_bf16(qh[1][0].f, fh0, sc1, 0, 0, 0);
            sc1 = __builtin_amdgcn_mfma_f32_16x16x32_bf16(qh[1][0].f, fl0, sc1, 0, 0, 0);
            sc1 = __builtin_amdgcn_mfma_f32_16x16x32_bf16(ql[1][0].f, fh0, sc1, 0, 0, 0);
            sc1 = __builtin_amdgcn_mfma_f32_16x16x32_bf16(qh[1][1].f, fh1, sc1, 0, 0, 0);
            sc1 = __builtin_amdgcn_mfma_f32_16x16x32_bf16(qh[1][1].f, fl1, sc1, 0, 0, 0);
            sc1 = __builtin_amdgcn_mfma_f32_16x16x32_bf16(ql[1][1].f, fh1, sc1, 0, 0, 0);
            __builtin_amdgcn_s_setprio(0);
            float cbv = nt ? cbv1 : cbv0;
#pragma unroll
            for (int r = 0; r < 4; r++) {
                int row16 = quad * 4 + r;
                int rel0 = nt * 16 + c - row16 + 32;
                float rv0 = Ring[((rel0 >= 32) ? off_hi : off_lo)
                                 + row16 * 35 + (rel0 & 31)];
                sv[0][nt][r] = sc0[r] + rv0 + cbv;
                int rel1 = rel0 - 16;
                float rv1 = Ring[((rel1 >= 32) ? off_hi : off_lo)
                                 + (16 + row16) * 35 + (rel1 & 31)];
                sv[1][nt][r] = sc1[r] + rv1 + cbv;
            }
        }

        // p~ = bf16(exp(s - 8)); weights sum to exactly 1 via l = sum(p~).
#pragma unroll
        for (int rg = 0; rg < 2; rg++)
#pragma unroll
            for (int r = 0; r < 4; r++) {
                u16* pb = Pbuf + w * 1280 + (16 * rg + quad * 4 + r) * 40;
                pb[c]      = bf16_rne(__expf(sv[rg][0][r]));
                pb[16 + c] = bf16_rne(__expf(sv[rg][1][r]));
            }

        frag_u ph[2];
#pragma unroll
        for (int rg = 0; rg < 2; rg++) {
            // row-major [row][j] u16 layout == PV A-frag: one b128 read.
            const u16* pb = Pbuf + w * 1280 + (16 * rg + c) * 40 + quad * 8;
            *(uint4*)&ph[rg] = *(const uint4*)pb;
        }
        __builtin_amdgcn_s_setprio(1);
#pragma unroll
        for (int ntd = 0; ntd < 4; ntd++) {
            o[0][ntd] = __builtin_amdgcn_mfma_f32_16x16x32_bf16(ph[0].f, vfh[ntd], o[0][ntd], 0, 0, 0);
            o[0][ntd] = __builtin_amdgcn_mfma_f32_16x16x32_bf16(ph[0].f, vfl[ntd], o[0][ntd], 0, 0, 0);
            o[1][ntd] = __builtin_amdgcn_mfma_f32_16x16x32_bf16(ph[1].f, vfh[ntd], o[1][ntd], 0, 0, 0);
            o[1][ntd] = __builtin_amdgcn_mfma_f32_16x16x32_bf16(ph[1].f, vfl[ntd], o[1][ntd], 0, 0, 0);
        }
        // l accumulation: every column of mfma(p, ones) holds sum_j p[row,j].
        acc_l[0] = __builtin_amdgcn_mfma_f32_16x16x32_bf16(ph[0].f, onesf.f, acc_l[0], 0, 0, 0);
        acc_l[1] = __builtin_amdgcn_mfma_f32_16x16x32_bf16(ph[1].f, onesf.f, acc_l[1], 0, 0, 0);
        __builtin_amdgcn_s_setprio(0);
    }

    // Combine the two KV-half partials: pure sums (no max tracking).
    // Wave 1 parks (o, l) inside ITS OWN ring half (Ring+3360) — disjoint
    // from wave 0's live slots and dead for wave 1 here.
    float* scr = Ring + 3360;      // [32 rows][65] + l at [2080 + row]
    if (w == 1) {
#pragma unroll
        for (int rg = 0; rg < 2; rg++) {
#pragma unroll
            for (int nt = 0; nt < 4; nt++)
#pragma unroll
                for (int r = 0; r < 4; r++)
                    scr[(16 * rg + quad * 4 + r) * 65 + nt * 16 + c] = o[rg][nt][r];
            if (c == 0) {
#pragma unroll
                for (int r = 0; r < 4; r++)
                    scr[2080 + 16 * rg + quad * 4 + r] = acc_l[rg][r];
            }
        }
    }
    __syncthreads();
    // Wave 0 combines and writes finals to LDS (its own dead ring half),
    // then both waves granule-pack the 32x64 tile into the out-proj A-tile.
    float* Lp = Ring;              // [32][68] = 8.7 KB inside wave-0 ring
    if (w == 0) {
#pragma unroll
        for (int rg = 0; rg < 2; rg++)
#pragma unroll
            for (int r = 0; r < 4; r++) {
                int row16 = quad * 4 + r;
                int row32 = 16 * rg + row16;
                float invl = 1.0f / (acc_l[rg][r] + scr[2080 + row32]);
#pragma unroll
                for (int nt = 0; nt < 4; nt++)
                    Lp[row32 * 68 + nt * 16 + c] =
                        (o[rg][nt][r] + scr[row32 * 65 + nt * 16 + c]) * invl;
            }
    }
    __syncthreads();
    u16* dt = Aout + (size_t)((b * 64 + it) * 8 + h) * 4096;
#pragma unroll
    for (int pass = 0; pass < 2; pass++) {
        int idx = pass * 128 + tid;
        int rr = idx >> 3, f = idx & 7;
        float xs[8];
#pragma unroll
        for (int e = 0; e < 8; e++) xs[e] = Lp[rr * 68 + f * 8 + e];
        int s = f >> 2, kq = f & 3, nt2 = rr >> 4, n = rr & 15;
        int g = nt2 * 128 + n * 8 + ((4 * s + kq + 5 * n) & 7);
        pack_granule(xs, dt, g);
    }
}

// ---------------------------------------------------------------------------
extern "C" void kernel_launch(void* const* d_in, const int* in_sizes, int n_in,
                              void* d_out, int out_size, void* d_ws, size_t ws_size,
                              hipStream_t stream) {
    const float* query  = (const float*)d_in[0];
    const float* key_in = (const float*)d_in[1];
    const float* value  = (const float*)d_in[2];
    const float* Wq = (const float*)d_in[3];
    const float* bq = (const float*)d_in[4];
    const float* Wk = (const float*)d_in[5];
    const float* bk = (const float*)d_in[6];
    const float* Wv = (const float*)d_in[7];
    const float* bv = (const float*)d_in[8];
    const float* Wr = (const float*)d_in[9];
    const float* cb = (const float*)d_in[10];
    const float* rb = (const float*)d_in[11];
    const float* Wo = (const float*)d_in[12];
    const float* bo = (const float*)d_in[13];
    float* out = (float*)d_out;

    float* ws = (float*)d_ws;
    const size_t SL = (size_t)MM * DD;        // 2097152 floats (8 MB) per slot
    // Slot map (R18): s0 PePk -> Qpk | s1 Kpk | s2 Vpk | s3 Rpk
    //   s4 Apk_v -> Apk_o | s5 Apk_k | s6 Apk_q
    //   s7 Wpk (5 MB) + cbk + rbrk
    u16*   PePk = (u16*)ws;
    u16*   Qpk  = (u16*)ws;
    u16*   Kpk  = (u16*)(ws + 1 * SL);
    u16*   Vpk  = (u16*)(ws + 2 * SL);
    u16*   Rpk  = (u16*)(ws + 3 * SL);
    u16*   s4   = (u16*)(ws + 4 * SL);
    u16*   s5   = (u16*)(ws + 5 * SL);
    u16*   s6   = (u16*)(ws + 6 * SL);
    u16*   Wpk  = (u16*)(ws + 7 * SL);
    float* cbk  = ws + 7 * SL + 1310720;      // [H*B*T]
    float* rbrk = cbk + BB * TT * HH;         // [H*2T]

    // ONE launch for every prepack (weights, pe, Q/K/V A-operands)
    prepack_all_kernel<<<4736, 256, 0, stream>>>(
        Wq, Wk, Wv, Wr, Wo, Wpk, PePk,
        query, key_in, value, s6, s5, s4);

    // rel_k GEMM -> packed R (x1/8) + rbrk (reads pe in s0; frees s0)
    gemm_relk_kernel<<<512, 256, 0, stream>>>(PePk, Wpk + 3 * WSZ, rb, Rpk, rbrk);

    // fused Q/K/V projection GEMMs (Q packed raw, K packed x1/8 + cbk, V)
    gemm3_mfma_kernel<<<1536, 256, 0, stream>>>(s6, s5, s4, Wpk, bq, bk, bv,
                                                cb, Qpk, Kpk, Vpk, cbk);

    // attention -> packed out-proj A operand directly (s4 reuse)
    attn_mfma_kernel<<<BB * HH * (TT / 32), 128, 0, stream>>>(
        Qpk, Kpk, Vpk, Rpk, cbk, rbrk, s4);

    // output projection
    gemm_mfma_kernel<<<512, 256, 0, stream>>>(s4, Wpk + 4 * WSZ, bo, out);
}

// Round 15
// 231.911 us; speedup vs baseline: 1.1425x; 1.1425x over previous
//
#include <hip/hip_runtime.h>
#include <math.h>

// Problem constants: B=2, T=2048, H=8, Dk=64, D=512
#define BB 2
#define TT 2048
#define HH 8
#define DK 64
#define DD 512
#define MM (BB * TT)
#define WSZ (128 * 4096)   // u16 per packed weight

typedef unsigned int u32;
typedef unsigned short u16;
typedef __bf16 bf16x8 __attribute__((ext_vector_type(8)));
typedef float f32x4 __attribute__((ext_vector_type(4)));

union frag_u { bf16x8 f; u16 u[8]; u32 w[4]; };

// fp32 -> bf16 hi + bf16 lo (RNE both); x ~= hi + lo to ~2^-20 rel.
__device__ __forceinline__ void split2(float x, u16& h, u16& l) {
    u32 u = __float_as_uint(x);
    u32 hi = (u + 0x7fffu + ((u >> 16) & 1u)) >> 16;
    float hif = __uint_as_float(hi << 16);
    float lof = x - hif;                       // exact
    u32 ul = __float_as_uint(lof);
    u32 lo = (ul + 0x7fffu + ((ul >> 16) & 1u)) >> 16;
    h = (u16)hi; l = (u16)lo;
}
// fp32 -> bf16 RNE (hi only)
__device__ __forceinline__ u16 bf16_rne(float x) {
    u32 u = __float_as_uint(x);
    return (u16)((u + 0x7fffu + ((u >> 16) & 1u)) >> 16);
}

// async global->LDS, 16B per lane, LDS dest = wave-uniform base + lane*16
__device__ __forceinline__ void load_lds16(const void* g, void* l) {
    __builtin_amdgcn_global_load_lds(
        (const __attribute__((address_space(1))) void*)g,
        (__attribute__((address_space(3))) void*)l, 16, 0, 0);
}

// ---------------------------------------------------------------------------
// Granule pack helper: 8 fp32 -> hi/lo uint4 pair at granule g of dst tile.
// ---------------------------------------------------------------------------
__device__ __forceinline__ void pack_granule(const float* xs, u16* dt, int g) {
    u32 hw[4], lw[4];
#pragma unroll
    for (int e = 0; e < 4; e++) {
        u16 h0, l0, h1, l1;
        split2(xs[2 * e], h0, l0);
        split2(xs[2 * e + 1], h1, l1);
        hw[e] = (u32)h0 | ((u32)h1 << 16);
        lw[e] = (u32)l0 | ((u32)l1 << 16);
    }
    *(uint4*)(dt + g * 8)        = make_uint4(hw[0], hw[1], hw[2], hw[3]);
    *(uint4*)(dt + 2048 + g * 8) = make_uint4(lw[0], lw[1], lw[2], lw[3]);
}

// ---------------------------------------------------------------------------
// Prepack a GEMM A-operand: fp32 [4096,512] -> 32-row x 64-k hi/lo granule
// tiles. bid: rb = bid>>3 (row-block), kb = bid&7 (k-block).
// ---------------------------------------------------------------------------
__device__ __forceinline__ void prepack_a_body(
    const float* __restrict__ src, u16* __restrict__ dst, int bid, int tid) {
    const int r = tid >> 3, f = tid & 7;
    const float* p = src + ((size_t)(bid >> 3) * 32 + r) * 512
                         + (size_t)(bid & 7) * 64 + f * 8;
    float4 a  = *(const float4*)p;
    float4 b4 = *(const float4*)(p + 4);
    float xs[8] = {a.x, a.y, a.z, a.w, b4.x, b4.y, b4.z, b4.w};
    const int s = f >> 2, kq = f & 3, nt = r >> 4, n = r & 15;
    const int g = nt * 128 + n * 8 + ((4 * s + kq + 5 * n) & 7);
    pack_granule(xs, dst + (size_t)bid * 4096, g);
}

// ---------------------------------------------------------------------------
// R17 FUSED all prepacks (independent work, ONE launch). Grid 4736:
//   bid < 640       : 5 weight matrices -> B-frag granule tiles (LDS transp)
//   640 <= bid <1664: sinusoid pe (fp64, matches numpy) -> packed A tiles
//   bid >= 1664     : Q/K/V A-prepack (reads raw inputs only)
// ---------------------------------------------------------------------------
__global__ __launch_bounds__(256) void prepack_all_kernel(
    const float* __restrict__ W0, const float* __restrict__ W1,
    const float* __restrict__ W2, const float* __restrict__ W3,
    const float* __restrict__ W4, u16* __restrict__ dstW,
    u16* __restrict__ dstPe,
    const float* __restrict__ sq, const float* __restrict__ sk,
    const float* __restrict__ sv, u16* __restrict__ dq,
    u16* __restrict__ dk, u16* __restrict__ dv) {
    __shared__ float tw[64][36];
    const int tid = threadIdx.x;
    if (blockIdx.x < 640) {
        const int bid = blockIdx.x;
        const int widx = bid >> 7, loc = bid & 127;
        const int nb2 = loc >> 3, kb = loc & 7;
        const float* Wsrc = widx == 0 ? W0 : widx == 1 ? W1 : widx == 2 ? W2
                          : widx == 3 ? W3 : W4;
        const int kl = tid >> 2, gr = tid & 3;
        const float* p = Wsrc + (size_t)(kb * 64 + kl) * 512 + nb2 * 32 + gr * 8;
        float4 a  = *(const float4*)p;
        float4 b4 = *(const float4*)(p + 4);
        *(float4*)&tw[kl][gr * 8]     = a;
        *(float4*)&tw[kl][gr * 8 + 4] = b4;
        __syncthreads();
        const int n5 = tid >> 3, f = tid & 7, s = f >> 2, kq = f & 3;
        float xs[8];
#pragma unroll
        for (int e = 0; e < 8; e++) xs[e] = tw[s * 32 + kq * 8 + e][n5];
        const int n = n5 & 15, nt = n5 >> 4;
        const int g = nt * 128 + n * 8 + ((4 * s + kq + 5 * n) & 7);
        pack_granule(xs, dstW + (size_t)bid * 4096, g);
    } else if (blockIdx.x < 1664) {
        const int bid = blockIdx.x - 640;
        const int r = tid >> 3, f = tid & 7;
        const int m  = (bid >> 3) * 32 + r;          // pe row
        const int c0 = (bid & 7) * 64 + f * 8;       // col base
        float xs[8];
#pragma unroll
        for (int e = 0; e < 8; e++) {
            int col = c0 + e;
            int j = col & 255;
            double inv_freq = exp((double)(-2 * j) * (9.210340371976184 / 512.0));
            double ang = (double)(TT - m) * inv_freq;
            xs[e] = (col < 256) ? (float)sin(ang) : (float)cos(ang);
        }
        const int s = f >> 2, kq = f & 3, nt = r >> 4, n = r & 15;
        const int g = nt * 128 + n * 8 + ((4 * s + kq + 5 * n) & 7);
        pack_granule(xs, dstPe + (size_t)bid * 4096, g);
    } else {
        const int bid = blockIdx.x - 1664;
        const int sel = bid >> 10, sub = bid & 1023;
        const float* s = sel == 0 ? sq : sel == 1 ? sk : sv;
        u16* d = sel == 0 ? dq : sel == 1 ? dk : dv;
        prepack_a_body(s, d, sub, tid);
    }
}

// ---------------------------------------------------------------------------
// MFMA GEMM, bf16 hi/lo emulation: C[4096,512] = A @ W + bias via prepacked
// granule tiles. 64x64 tile, BK=64, 4 waves each 32x32.
// C = Ah*Wh + Ah*Wl + Al*Wh. XCD swizzle: bx = nb*64 + mp.
// R20 = REVERT to the R12 staged main loop (double-buffered global_load_lds,
// 1 barrier/kstep). R13's direct-L2 loop regressed +21 us: it doubled L2
// read traffic (per-wave instead of per-block operand reads, ~768 MB for
// gemm3 ~ 22 us of pure L2 BW) and lost the async DMA path. The staged
// barrier drain is the cheaper structure here.
// FUSED EPILOGUES (EPI):
//   EPI 0: plain fp32 C write (out proj)
//   EPI 1: packed K tiles SCALED BY 1/8 + cbk dot (cb . k * 0.125 - 8)
//   EPI 2: packed V tiles (transposed V-frag layout)
//   EPI 3: packed R chunks SCALED BY 1/8 + rbrk dot (rb . relk * 0.125)
//   EPI 4: packed Q as A-granule tiles (Q proj; attn reads frags directly)
// R18: the attention 1/8 logit scale is folded into the K and R packs
// (power-of-2: split2(x/8) == split2(x)/8 EXACTLY). Q packed raw.
// ---------------------------------------------------------------------------
__device__ __forceinline__ void gemm_full(
    const u16* __restrict__ Apk, const u16* __restrict__ Wpk,
    const float* __restrict__ bias, float* __restrict__ C,
    u16* __restrict__ Ppk, const float* __restrict__ dotv,
    float* __restrict__ dotout, int EPI, int bx, int tid) {
    __shared__ __align__(16) u16 Stage[2][16384];   // [half][A0 A1 W0 W1]

    const int w = tid >> 6, lane = tid & 63, quad = lane >> 4, c = lane & 15;
    const int mp = bx & 63, nb = bx >> 6;
    const int mq = w >> 1, nq = w & 1;

    auto stage_async = [&](int kb, int half) {
        const u16* s = (w < 2)
            ? Apk + (size_t)((2 * mp + w) * 8 + kb) * 4096
            : Wpk + (size_t)((2 * nb + (w & 1)) * 8 + kb) * 4096;
        const u16* g = s + lane * 8;
        u16* d = Stage[half] + w * 4096;
#pragma unroll
        for (int u2 = 0; u2 < 8; u2++)
            load_lds16(g + u2 * 512, d + u2 * 512);
    };

    stage_async(0, 0);

    f32x4 acc[2][2];
#pragma unroll
    for (int mh = 0; mh < 2; mh++)
#pragma unroll
        for (int nh = 0; nh < 2; nh++) acc[mh][nh] = (f32x4){0.f, 0.f, 0.f, 0.f};

    for (int kb = 0; kb < 8; kb++) {
        const int half = kb & 1;
        __syncthreads();          // drains this half's DMA; prior reads done
        if (kb < 7) stage_async(kb + 1, 1 - half);
        const u16* Ab = Stage[half] + mq * 4096;
        const u16* Wb = Stage[half] + 8192 + nq * 4096;
#pragma unroll
        for (int s = 0; s < 2; s++) {
            bf16x8 ah[2], al[2], wh[2], wl[2];
#pragma unroll
            for (int t = 0; t < 2; t++) {
                int g = (t << 7) + (c << 3) + (((s << 2) + quad + 5 * c) & 7);
                ah[t] = *(const bf16x8*)(Ab + g * 8);
                al[t] = *(const bf16x8*)(Ab + 2048 + g * 8);
                wh[t] = *(const bf16x8*)(Wb + g * 8);
                wl[t] = *(const bf16x8*)(Wb + 2048 + g * 8);
            }
#pragma unroll
            for (int mh = 0; mh < 2; mh++)
#pragma unroll
                for (int nh = 0; nh < 2; nh++) {
                    acc[mh][nh] = __builtin_amdgcn_mfma_f32_16x16x32_bf16(
                        ah[mh], wh[nh], acc[mh][nh], 0, 0, 0);
                    acc[mh][nh] = __builtin_amdgcn_mfma_f32_16x16x32_bf16(
                        ah[mh], wl[nh], acc[mh][nh], 0, 0, 0);
                    acc[mh][nh] = __builtin_amdgcn_mfma_f32_16x16x32_bf16(
                        al[mh], wh[nh], acc[mh][nh], 0, 0, 0);
                }
        }
    }

    const int n0 = nb * 64 + nq * 32;
    float bv0 = bias ? bias[n0 + c] : 0.f;
    float bv1 = bias ? bias[n0 + 16 + c] : 0.f;

    if (EPI == 0) {
        const int m0 = mp * 64 + mq * 32;
#pragma unroll
        for (int mh = 0; mh < 2; mh++)
#pragma unroll
            for (int r = 0; r < 4; r++) {
                size_t row = (size_t)(m0 + mh * 16 + quad * 4 + r) * 512;
                C[row + n0 + c]      = acc[mh][0][r] + bv0;
                C[row + n0 + 16 + c] = acc[mh][1][r] + bv1;
            }
        return;
    }

    // ---- packing epilogues: C tile -> LDS fp32, then granule-pack ----
    __syncthreads();                               // all waves done w/ Stage
    float (*Cl)[68] = (float (*)[68])Stage;        // [64][68] = 17.4 KB
    {
        const int rbase = mq * 32;
#pragma unroll
        for (int mh = 0; mh < 2; mh++)
#pragma unroll
            for (int r = 0; r < 4; r++) {
                int row = rbase + mh * 16 + quad * 4 + r;
                Cl[row][nq * 32 + c]      = acc[mh][0][r] + bv0;
                Cl[row][nq * 32 + 16 + c] = acc[mh][1][r] + bv1;
            }
    }
    __syncthreads();

    if (EPI == 2) {                                // V tiles (transposed frag)
        const int b = mp >> 5, jt0 = (mp & 31) * 2;
        const int d = tid >> 2, kq = tid & 3;
        const int n = d & 15;
        const int g = (d >> 4) * 64 + n * 4 + ((kq + (n >> 1)) & 3);
#pragma unroll
        for (int ht = 0; ht < 2; ht++) {
            float xs[8];
#pragma unroll
            for (int e = 0; e < 8; e++) xs[e] = Cl[ht * 32 + kq * 8 + e][d];
            u16* dt = Ppk + (size_t)(b * 512 + nb * 64 + jt0 + ht) * 4096;
            pack_granule(xs, dt, g);
        }
        return;
    }

    // EPI 1 (K, x1/8) / EPI 3 (R, x1/8) / EPI 4 (Q, raw): B/A-frag granule
    {
        const float scl = (EPI == 4) ? 1.0f : 0.125f;
        const int rr = tid >> 3, f = tid & 7;
        const int s = f >> 2, kq = f & 3, nt = rr >> 4, n = rr & 15;
        const int g = nt * 128 + n * 8 + ((4 * s + kq + 5 * n) & 7);
#pragma unroll
        for (int ht = 0; ht < 2; ht++) {
            float xs[8];
#pragma unroll
            for (int e = 0; e < 8; e++) xs[e] = Cl[ht * 32 + rr][f * 8 + e] * scl;
            size_t tidx = (EPI == 1)
                ? (size_t)((mp >> 5) * 512 + nb * 64 + (mp & 31) * 2 + ht)
                : (EPI == 3)
                ? (size_t)(nb * 128 + mp * 2 + ht)
                : (size_t)((mp * 2 + ht) * 8 + nb);
            pack_granule(xs, Ppk + tidx * 4096, g);
        }
    }
    if (EPI != 4 && tid < 64) {                    // bias-fold dot, 1 row/lane
        const float* dv = dotv + nb * 64;
        const float* rowp = Cl[tid];
        float sacc = 0.f;
#pragma unroll
        for (int d = 0; d < 64; d++) sacc += dv[d] * rowp[d];
        int m = mp * 64 + tid;
        if (EPI == 1) {
            int b = m >> 11, t = m & 2047;
            dotout[((size_t)nb * BB + b) * TT + t] = sacc * 0.125f - 8.0f;
        } else {
            dotout[(size_t)nb * 4096 + m] = sacc * 0.125f;
        }
    }
}

__global__ __launch_bounds__(256, 2) void gemm_mfma_kernel(
    const u16* __restrict__ Apk, const u16* __restrict__ Wpk,
    const float* __restrict__ bias, float* __restrict__ C) {
    gemm_full(Apk, Wpk, bias, C, nullptr, nullptr, nullptr, 0,
              blockIdx.x, threadIdx.x);
}

// rel_k GEMM: pe-packed A x Wr -> packed R chunks (x1/8) + rbrk. Grid 512.
__global__ __launch_bounds__(256, 2) void gemm_relk_kernel(
    const u16* __restrict__ Apk, const u16* __restrict__ Wpk,
    const float* __restrict__ rb, u16* __restrict__ Rpk,
    float* __restrict__ rbrk) {
    gemm_full(Apk, Wpk, nullptr, nullptr, Rpk, rb, rbrk, 3,
              blockIdx.x, threadIdx.x);
}

// Fused Q/K/V projection GEMMs: grid 1536, widx = bx>>9.
// widx0 -> packed Q A-tiles (EPI4); widx1 -> packed K (x1/8) + cbk;
// widx2 -> packed V.
__global__ __launch_bounds__(256, 2) void gemm3_mfma_kernel(
    const u16* __restrict__ Aq, const u16* __restrict__ Ak,
    const u16* __restrict__ Av, const u16* __restrict__ Wpk,
    const float* __restrict__ bq, const float* __restrict__ bk,
    const float* __restrict__ bv, const float* __restrict__ cb,
    u16* __restrict__ Qpk, u16* __restrict__ Kpk, u16* __restrict__ Vpk,
    float* __restrict__ cbk) {
    const int widx = blockIdx.x >> 9, bx = blockIdx.x & 511;
    const u16* A = widx == 0 ? Aq : widx == 1 ? Ak : Av;
    const u16* W = Wpk + (size_t)widx * WSZ;
    const float* bias = widx == 0 ? bq : widx == 1 ? bk : bv;
    u16* P = widx == 0 ? Qpk : widx == 1 ? Kpk : Vpk;
    const int EPI = widx == 0 ? 4 : widx;
    gemm_full(A, W, bias, nullptr, P, widx == 1 ? cb : nullptr,
              widx == 1 ? cbk : nullptr, EPI, bx, threadIdx.x);
}

// ---------------------------------------------------------------------------
// MFMA flash attention with Transformer-XL rel-shift (unchanged from R12,
// the best measured attn @ ~103 us).
// R8-R14: no-max softmax (-8 shift in cbk), l = mfma(p, ones), KV-split
// 2-wave blocks, no in-loop barriers, 3-slot mod-3 ring, per-head XCD-L2
// affinity, 32 q-rows/wave, packed A-tile epilogue, V-load hoist (R17).
// R18a Q-DIRECT: Q fragments straight from packed Q A-tiles; 1/8 scale in
// the K/R packs (bit-identical). R18b HI-ONLY P with the V-hoist cover.
// ---------------------------------------------------------------------------
__global__ __launch_bounds__(128, 2) void attn_mfma_kernel(
    const u16* __restrict__ Qpk, const u16* __restrict__ Kpk,
    const u16* __restrict__ Vpk, const u16* __restrict__ Rpk,
    const float* __restrict__ cbk, const float* __restrict__ rbrk,
    u16* __restrict__ Aout) {
    __shared__ float Ring[2 * 3 * 1120];           // [wave][slot][32][35]
    __shared__ __align__(16) u16 Pbuf[2 * 1280];   // [wave][32 rows][40]

    const int tid = threadIdx.x;
    const int w = tid >> 6, lane = tid & 63, quad = lane >> 4, c = lane & 15;
    const int bx = blockIdx.x;
    const int h = bx & 7, b = (bx >> 3) & 1, it = bx >> 4;   // h in low bits
    const int i0 = it * 32;

    // Q fragments direct from packed A-tile: [rg][s]
    frag_u qh[2][2], ql[2][2];
    {
        const u16* Qt = Qpk + (size_t)((b * 64 + it) * 8 + h) * 4096;
#pragma unroll
        for (int rg = 0; rg < 2; rg++)
#pragma unroll
            for (int s = 0; s < 2; s++) {
                int g = (rg << 7) + (c << 3) + (((s << 2) + quad + 5 * c) & 7);
                qh[rg][s].f = *(const bf16x8*)(Qt + g * 8);
                ql[rg][s].f = *(const bf16x8*)(Qt + 2048 + g * 8);
            }
    }

    // all-ones B fragment for row-sum MFMAs (l accumulation)
    frag_u onesf;
#pragma unroll
    for (int j2 = 0; j2 < 8; j2++) onesf.u[j2] = 0x3f80u;   // bf16 1.0

    const u16* Ktiles  = Kpk + (size_t)(b * HH + h) * 64 * 4096;
    const u16* Vtiles  = Vpk + (size_t)(b * HH + h) * 64 * 4096;
    const u16* Rchunks = Rpk + (size_t)h * 128 * 4096;
    const float* rbrk_h = rbrk + (size_t)h * (2 * TT);
    const float* cbk_h  = cbk + ((size_t)h * BB + b) * TT;

    auto read_kr = [&](const u16* reg, int nt, int s, bf16x8& fh, bf16x8& fl) {
        int g = (nt << 7) + (c << 3) + (((s << 2) + quad + 5 * c) & 7);
        fh = *(const bf16x8*)(reg + g * 8);
        fl = *(const bf16x8*)(reg + 2048 + g * 8);
    };
    auto read_v = [&](const u16* Vb, int ntd, bf16x8& fh, bf16x8& fl) {
        int g = ntd * 64 + c * 4 + ((quad + (c >> 1)) & 3);
        fh = *(const bf16x8*)(Vb + g * 8);
        fl = *(const bf16x8*)(Vb + 2048 + g * 8);
    };

    // produce: Q(32 rows) . (R/8)-chunk -> ring slot [32][35]
    auto produce = [&](int cidx) {
        const u16* Rc = Rchunks + (size_t)cidx * 4096;
        float* ringw = Ring + (w * 3 + cidx % 3) * 1120;
#pragma unroll
        for (int ntp = 0; ntp < 2; ntp++) {
            f32x4 a0 = {0.f, 0.f, 0.f, 0.f};
            f32x4 a1 = {0.f, 0.f, 0.f, 0.f};
#pragma unroll
            for (int s = 0; s < 2; s++) {
                int g = (ntp << 7) + (c << 3) + (((s << 2) + quad + 5 * c) & 7);
                bf16x8 fh = *(const bf16x8*)(Rc + g * 8);
                bf16x8 fl = *(const bf16x8*)(Rc + 2048 + g * 8);
                a0 = __builtin_amdgcn_mfma_f32_16x16x32_bf16(qh[0][s].f, fh, a0, 0, 0, 0);
                a0 = __builtin_amdgcn_mfma_f32_16x16x32_bf16(qh[0][s].f, fl, a0, 0, 0, 0);
                a0 = __builtin_amdgcn_mfma_f32_16x16x32_bf16(ql[0][s].f, fh, a0, 0, 0, 0);
                a1 = __builtin_amdgcn_mfma_f32_16x16x32_bf16(qh[1][s].f, fh, a1, 0, 0, 0);
                a1 = __builtin_amdgcn_mfma_f32_16x16x32_bf16(qh[1][s].f, fl, a1, 0, 0, 0);
                a1 = __builtin_amdgcn_mfma_f32_16x16x32_bf16(ql[1][s].f, fh, a1, 0, 0, 0);
            }
            float rbv = rbrk_h[cidx * 32 + ntp * 16 + c];
            int mpos = ntp * 16 + c;
#pragma unroll
            for (int r = 0; r < 4; r++)
                ringw[(quad * 4 + r) * 35 + mpos] = a0[r] + rbv;
#pragma unroll
            for (int r = 0; r < 4; r++)
                ringw[(16 + quad * 4 + r) * 35 + mpos] = a1[r] + rbv;
        }
    };

    // base m at (row i0, local j=0); aligned to 32 since i0,j0 = 0 mod 32.
    const int base = TT - i0 + 1024 * w;
    const int F = (base >> 5) - 1;      // first chunk of the t=0 window
    produce(F);
    produce(F + 1);

    f32x4 o[2][4];
    f32x4 acc_l[2];
#pragma unroll
    for (int rg = 0; rg < 2; rg++) {
        acc_l[rg] = (f32x4){0.f, 0.f, 0.f, 0.f};
#pragma unroll
        for (int nt = 0; nt < 4; nt++) o[rg][nt] = (f32x4){0.f, 0.f, 0.f, 0.f};
    }

    for (int t = 0; t < 32; t++) {
        const int j0 = 1024 * w + 32 * t;
        const u16* Kb = Ktiles + (size_t)(w * 32 + t) * 4096;
        const u16* Vb = Vtiles + (size_t)(w * 32 + t) * 4096;

        // V loads issued FIRST — consumed at PV (end of body), covered by
        // produce + QK + softmax in between (R17).
        bf16x8 vfh[4], vfl[4];
#pragma unroll
        for (int ntd = 0; ntd < 4; ntd++) read_v(Vb, ntd, vfh[ntd], vfl[ntd]);

        int cnext = F + t + 2;
        if (cnext < 128) produce(cnext);

        // window chunks {F+t, F+t+1}; slots mod 3
        const int slo = (F + t) % 3;
        const int shi = (slo == 2) ? 0 : slo + 1;
        const int off_lo = (w * 3 + slo) * 1120;
        const int off_hi = (w * 3 + shi) * 1120;
        float cbv0 = cbk_h[j0 + c];
        float cbv1 = cbk_h[j0 + 16 + c];
        float sv[2][2][4];
#pragma unroll
        for (int nt = 0; nt < 2; nt++) {
            f32x4 sc0 = {0.f, 0.f, 0.f, 0.f};
            f32x4 sc1 = {0.f, 0.f, 0.f, 0.f};
            bf16x8 fh0, fl0, fh1, fl1;
            read_kr(Kb, nt, 0, fh0, fl0);
            read_kr(Kb, nt, 1, fh1, fl1);
            __builtin_amdgcn_s_setprio(1);
            sc0 = __builtin_amdgcn_mfma_f32_16x16x32_bf16(qh[0][0].f, fh0, sc0, 0, 0, 0);
            sc0 = __builtin_amdgcn_mfma_f32_16x16x32_bf16(qh[0][0].f, fl0, sc0, 0, 0, 0);
            sc0 = __builtin_amdgcn_mfma_f32_16x16x32_bf16(ql[0][0].f, fh0, sc0, 0, 0, 0);
            sc0 = __builtin_amdgcn_mfma_f32_16x16x32_bf16(qh[0][1].f, fh1, sc0, 0, 0, 0);
            sc0 = __builtin_amdgcn_mfma_f32_16x16x32_bf16(qh[0][1].f, fl1, sc0, 0, 0, 0);
            sc0 = __builtin_amdgcn_mfma_f32_16x16x32_bf16(ql[0][1].f, fh1, sc0, 0, 0, 0);
            sc1 = __builtin_amdgcn_mfma_f32_16x16x32_bf16(qh[1][0].f, fh0, sc1, 0, 0, 0);
            sc1 = __builtin_amdgcn_mfma_f32_16x16x32_bf16(qh[1][0].f, fl0, sc1, 0, 0, 0);
            sc1 = __builtin_amdgcn_mfma_f32_16x16x32_bf16(ql[1][0].f, fh0, sc1, 0, 0, 0);
            sc1 = __builtin_amdgcn_mfma_f32_16x16x32_bf16(qh[1][1].f, fh1, sc1, 0, 0, 0);
            sc1 = __builtin_amdgcn_mfma_f32_16x16x32_bf16(qh[1][1].f, fl1, sc1, 0, 0, 0);
            sc1 = __builtin_amdgcn_mfma_f32_16x16x32_bf16(ql[1][1].f, fh1, sc1, 0, 0, 0);
            __builtin_amdgcn_s_setprio(0);
            float cbv = nt ? cbv1 : cbv0;
#pragma unroll
            for (int r = 0; r < 4; r++) {
                int row16 = quad * 4 + r;
                int rel0 = nt * 16 + c - row16 + 32;
                float rv0 = Ring[((rel0 >= 32) ? off_hi : off_lo)
                                 + row16 * 35 + (rel0 & 31)];
                sv[0][nt][r] = sc0[r] + rv0 + cbv;
                int rel1 = rel0 - 16;
                float rv1 = Ring[((rel1 >= 32) ? off_hi : off_lo)
                                 + (16 + row16) * 35 + (rel1 & 31)];
                sv[1][nt][r] = sc1[r] + rv1 + cbv;
            }
        }

        // p~ = bf16(exp(s - 8)); weights sum to exactly 1 via l = sum(p~).
#pragma unroll
        for (int rg = 0; rg < 2; rg++)
#pragma unroll
            for (int r = 0; r < 4; r++) {
                u16* pb = Pbuf + w * 1280 + (16 * rg + quad * 4 + r) * 40;
                pb[c]      = bf16_rne(__expf(sv[rg][0][r]));
                pb[16 + c] = bf16_rne(__expf(sv[rg][1][r]));
            }

        frag_u ph[2];
#pragma unroll
        for (int rg = 0; rg < 2; rg++) {
            // row-major [row][j] u16 layout == PV A-frag: one b128 read.
            const u16* pb = Pbuf + w * 1280 + (16 * rg + c) * 40 + quad * 8;
            *(uint4*)&ph[rg] = *(const uint4*)pb;
        }
        __builtin_amdgcn_s_setprio(1);
#pragma unroll
        for (int ntd = 0; ntd < 4; ntd++) {
            o[0][ntd] = __builtin_amdgcn_mfma_f32_16x16x32_bf16(ph[0].f, vfh[ntd], o[0][ntd], 0, 0, 0);
            o[0][ntd] = __builtin_amdgcn_mfma_f32_16x16x32_bf16(ph[0].f, vfl[ntd], o[0][ntd], 0, 0, 0);
            o[1][ntd] = __builtin_amdgcn_mfma_f32_16x16x32_bf16(ph[1].f, vfh[ntd], o[1][ntd], 0, 0, 0);
            o[1][ntd] = __builtin_amdgcn_mfma_f32_16x16x32_bf16(ph[1].f, vfl[ntd], o[1][ntd], 0, 0, 0);
        }
        // l accumulation: every column of mfma(p, ones) holds sum_j p[row,j].
        acc_l[0] = __builtin_amdgcn_mfma_f32_16x16x32_bf16(ph[0].f, onesf.f, acc_l[0], 0, 0, 0);
        acc_l[1] = __builtin_amdgcn_mfma_f32_16x16x32_bf16(ph[1].f, onesf.f, acc_l[1], 0, 0, 0);
        __builtin_amdgcn_s_setprio(0);
    }

    // Combine the two KV-half partials: pure sums (no max tracking).
    // Wave 1 parks (o, l) inside ITS OWN ring half (Ring+3360) — disjoint
    // from wave 0's live slots and dead for wave 1 here.
    float* scr = Ring + 3360;      // [32 rows][65] + l at [2080 + row]
    if (w == 1) {
#pragma unroll
        for (int rg = 0; rg < 2; rg++) {
#pragma unroll
            for (int nt = 0; nt < 4; nt++)
#pragma unroll
                for (int r = 0; r < 4; r++)
                    scr[(16 * rg + quad * 4 + r) * 65 + nt * 16 + c] = o[rg][nt][r];
            if (c == 0) {
#pragma unroll
                for (int r = 0; r < 4; r++)
                    scr[2080 + 16 * rg + quad * 4 + r] = acc_l[rg][r];
            }
        }
    }
    __syncthreads();
    // Wave 0 combines and writes finals to LDS (its own dead ring half),
    // then both waves granule-pack the 32x64 tile into the out-proj A-tile.
    float* Lp = Ring;              // [32][68] = 8.7 KB inside wave-0 ring
    if (w == 0) {
#pragma unroll
        for (int rg = 0; rg < 2; rg++)
#pragma unroll
            for (int r = 0; r < 4; r++) {
                int row16 = quad * 4 + r;
                int row32 = 16 * rg + row16;
                float invl = 1.0f / (acc_l[rg][r] + scr[2080 + row32]);
#pragma unroll
                for (int nt = 0; nt < 4; nt++)
                    Lp[row32 * 68 + nt * 16 + c] =
                        (o[rg][nt][r] + scr[row32 * 65 + nt * 16 + c]) * invl;
            }
    }
    __syncthreads();
    u16* dt = Aout + (size_t)((b * 64 + it) * 8 + h) * 4096;
#pragma unroll
    for (int pass = 0; pass < 2; pass++) {
        int idx = pass * 128 + tid;
        int rr = idx >> 3, f = idx & 7;
        float xs[8];
#pragma unroll
        for (int e = 0; e < 8; e++) xs[e] = Lp[rr * 68 + f * 8 + e];
        int s = f >> 2, kq = f & 3, nt2 = rr >> 4, n = rr & 15;
        int g = nt2 * 128 + n * 8 + ((4 * s + kq + 5 * n) & 7);
        pack_granule(xs, dt, g);
    }
}

// ---------------------------------------------------------------------------
extern "C" void kernel_launch(void* const* d_in, const int* in_sizes, int n_in,
                              void* d_out, int out_size, void* d_ws, size_t ws_size,
                              hipStream_t stream) {
    const float* query  = (const float*)d_in[0];
    const float* key_in = (const float*)d_in[1];
    const float* value  = (const float*)d_in[2];
    const float* Wq = (const float*)d_in[3];
    const float* bq = (const float*)d_in[4];
    const float* Wk = (const float*)d_in[5];
    const float* bk = (const float*)d_in[6];
    const float* Wv = (const float*)d_in[7];
    const float* bv = (const float*)d_in[8];
    const float* Wr = (const float*)d_in[9];
    const float* cb = (const float*)d_in[10];
    const float* rb = (const float*)d_in[11];
    const float* Wo = (const float*)d_in[12];
    const float* bo = (const float*)d_in[13];
    float* out = (float*)d_out;

    float* ws = (float*)d_ws;
    const size_t SL = (size_t)MM * DD;        // 2097152 floats (8 MB) per slot
    // Slot map (R18): s0 PePk -> Qpk | s1 Kpk | s2 Vpk | s3 Rpk
    //   s4 Apk_v -> Apk_o | s5 Apk_k | s6 Apk_q
    //   s7 Wpk (5 MB) + cbk + rbrk
    u16*   PePk = (u16*)ws;
    u16*   Qpk  = (u16*)ws;
    u16*   Kpk  = (u16*)(ws + 1 * SL);
    u16*   Vpk  = (u16*)(ws + 2 * SL);
    u16*   Rpk  = (u16*)(ws + 3 * SL);
    u16*   s4   = (u16*)(ws + 4 * SL);
    u16*   s5   = (u16*)(ws + 5 * SL);
    u16*   s6   = (u16*)(ws + 6 * SL);
    u16*   Wpk  = (u16*)(ws + 7 * SL);
    float* cbk  = ws + 7 * SL + 1310720;      // [H*B*T]
    float* rbrk = cbk + BB * TT * HH;         // [H*2T]

    // ONE launch for every prepack (weights, pe, Q/K/V A-operands)
    prepack_all_kernel<<<4736, 256, 0, stream>>>(
        Wq, Wk, Wv, Wr, Wo, Wpk, PePk,
        query, key_in, value, s6, s5, s4);

    // rel_k GEMM -> packed R (x1/8) + rbrk (reads pe in s0; frees s0)
    gemm_relk_kernel<<<512, 256, 0, stream>>>(PePk, Wpk + 3 * WSZ, rb, Rpk, rbrk);

    // fused Q/K/V projection GEMMs (Q packed raw, K packed x1/8 + cbk, V)
    gemm3_mfma_kernel<<<1536, 256, 0, stream>>>(s6, s5, s4, Wpk, bq, bk, bv,
                                                cb, Qpk, Kpk, Vpk, cbk);

    // attention -> packed out-proj A operand directly (s4 reuse)
    attn_mfma_kernel<<<BB * HH * (TT / 32), 128, 0, stream>>>(
        Qpk, Kpk, Vpk, Rpk, cbk, rbrk, s4);

    // output projection
    gemm_mfma_kernel<<<512, 256, 0, stream>>>(s4, Wpk + 4 * WSZ, bo, out);
}

// Round 16
// 223.335 us; speedup vs baseline: 1.1864x; 1.0384x over previous
//
#include <hip/hip_runtime.h>
#include <math.h>

// Problem constants: B=2, T=2048, H=8, Dk=64, D=512
#define BB 2
#define TT 2048
#define HH 8
#define DK 64
#define DD 512
#define MM (BB * TT)
#define WSZ (128 * 4096)   // u16 per packed weight

typedef unsigned int u32;
typedef unsigned short u16;
typedef __bf16 bf16x8 __attribute__((ext_vector_type(8)));
typedef float f32x4 __attribute__((ext_vector_type(4)));

union frag_u { bf16x8 f; u16 u[8]; u32 w[4]; };

// fp32 -> bf16 hi + bf16 lo (RNE both); x ~= hi + lo to ~2^-20 rel.
__device__ __forceinline__ void split2(float x, u16& h, u16& l) {
    u32 u = __float_as_uint(x);
    u32 hi = (u + 0x7fffu + ((u >> 16) & 1u)) >> 16;
    float hif = __uint_as_float(hi << 16);
    float lof = x - hif;                       // exact
    u32 ul = __float_as_uint(lof);
    u32 lo = (ul + 0x7fffu + ((ul >> 16) & 1u)) >> 16;
    h = (u16)hi; l = (u16)lo;
}
// fp32 -> bf16 RNE (hi only)
__device__ __forceinline__ u16 bf16_rne(float x) {
    u32 u = __float_as_uint(x);
    return (u16)((u + 0x7fffu + ((u >> 16) & 1u)) >> 16);
}

// async global->LDS, 16B per lane, LDS dest = wave-uniform base + lane*16
__device__ __forceinline__ void load_lds16(const void* g, void* l) {
    __builtin_amdgcn_global_load_lds(
        (const __attribute__((address_space(1))) void*)g,
        (__attribute__((address_space(3))) void*)l, 16, 0, 0);
}

// ---------------------------------------------------------------------------
// Granule pack helper: 8 fp32 -> hi/lo uint4 pair at granule g of dst tile.
// ---------------------------------------------------------------------------
__device__ __forceinline__ void pack_granule(const float* xs, u16* dt, int g) {
    u32 hw[4], lw[4];
#pragma unroll
    for (int e = 0; e < 4; e++) {
        u16 h0, l0, h1, l1;
        split2(xs[2 * e], h0, l0);
        split2(xs[2 * e + 1], h1, l1);
        hw[e] = (u32)h0 | ((u32)h1 << 16);
        lw[e] = (u32)l0 | ((u32)l1 << 16);
    }
    *(uint4*)(dt + g * 8)        = make_uint4(hw[0], hw[1], hw[2], hw[3]);
    *(uint4*)(dt + 2048 + g * 8) = make_uint4(lw[0], lw[1], lw[2], lw[3]);
}

// ---------------------------------------------------------------------------
// Prepack a GEMM A-operand: fp32 [4096,512] -> 32-row x 64-k hi/lo granule
// tiles. bid: rb = bid>>3 (row-block), kb = bid&7 (k-block).
// ---------------------------------------------------------------------------
__device__ __forceinline__ void prepack_a_body(
    const float* __restrict__ src, u16* __restrict__ dst, int bid, int tid) {
    const int r = tid >> 3, f = tid & 7;
    const float* p = src + ((size_t)(bid >> 3) * 32 + r) * 512
                         + (size_t)(bid & 7) * 64 + f * 8;
    float4 a  = *(const float4*)p;
    float4 b4 = *(const float4*)(p + 4);
    float xs[8] = {a.x, a.y, a.z, a.w, b4.x, b4.y, b4.z, b4.w};
    const int s = f >> 2, kq = f & 3, nt = r >> 4, n = r & 15;
    const int g = nt * 128 + n * 8 + ((4 * s + kq + 5 * n) & 7);
    pack_granule(xs, dst + (size_t)bid * 4096, g);
}

// ---------------------------------------------------------------------------
// R17 FUSED all prepacks (independent work, ONE launch). Grid 4736:
//   bid < 640       : 5 weight matrices -> B-frag granule tiles (LDS transp)
//   640 <= bid <1664: sinusoid pe (fp64, matches numpy) -> packed A tiles
//   bid >= 1664     : Q/K/V A-prepack (reads raw inputs only)
// ---------------------------------------------------------------------------
__global__ __launch_bounds__(256) void prepack_all_kernel(
    const float* __restrict__ W0, const float* __restrict__ W1,
    const float* __restrict__ W2, const float* __restrict__ W3,
    const float* __restrict__ W4, u16* __restrict__ dstW,
    u16* __restrict__ dstPe,
    const float* __restrict__ sq, const float* __restrict__ sk,
    const float* __restrict__ sv, u16* __restrict__ dq,
    u16* __restrict__ dk, u16* __restrict__ dv) {
    __shared__ float tw[64][36];
    const int tid = threadIdx.x;
    if (blockIdx.x < 640) {
        const int bid = blockIdx.x;
        const int widx = bid >> 7, loc = bid & 127;
        const int nb2 = loc >> 3, kb = loc & 7;
        const float* Wsrc = widx == 0 ? W0 : widx == 1 ? W1 : widx == 2 ? W2
                          : widx == 3 ? W3 : W4;
        const int kl = tid >> 2, gr = tid & 3;
        const float* p = Wsrc + (size_t)(kb * 64 + kl) * 512 + nb2 * 32 + gr * 8;
        float4 a  = *(const float4*)p;
        float4 b4 = *(const float4*)(p + 4);
        *(float4*)&tw[kl][gr * 8]     = a;
        *(float4*)&tw[kl][gr * 8 + 4] = b4;
        __syncthreads();
        const int n5 = tid >> 3, f = tid & 7, s = f >> 2, kq = f & 3;
        float xs[8];
#pragma unroll
        for (int e = 0; e < 8; e++) xs[e] = tw[s * 32 + kq * 8 + e][n5];
        const int n = n5 & 15, nt = n5 >> 4;
        const int g = nt * 128 + n * 8 + ((4 * s + kq + 5 * n) & 7);
        pack_granule(xs, dstW + (size_t)bid * 4096, g);
    } else if (blockIdx.x < 1664) {
        const int bid = blockIdx.x - 640;
        const int r = tid >> 3, f = tid & 7;
        const int m  = (bid >> 3) * 32 + r;          // pe row
        const int c0 = (bid & 7) * 64 + f * 8;       // col base
        float xs[8];
#pragma unroll
        for (int e = 0; e < 8; e++) {
            int col = c0 + e;
            int j = col & 255;
            double inv_freq = exp((double)(-2 * j) * (9.210340371976184 / 512.0));
            double ang = (double)(TT - m) * inv_freq;
            xs[e] = (col < 256) ? (float)sin(ang) : (float)cos(ang);
        }
        const int s = f >> 2, kq = f & 3, nt = r >> 4, n = r & 15;
        const int g = nt * 128 + n * 8 + ((4 * s + kq + 5 * n) & 7);
        pack_granule(xs, dstPe + (size_t)bid * 4096, g);
    } else {
        const int bid = blockIdx.x - 1664;
        const int sel = bid >> 10, sub = bid & 1023;
        const float* s = sel == 0 ? sq : sel == 1 ? sk : sv;
        u16* d = sel == 0 ? dq : sel == 1 ? dk : dv;
        prepack_a_body(s, d, sub, tid);
    }
}

// ---------------------------------------------------------------------------
// MFMA GEMM, bf16 hi/lo emulation: C[4096,512] = A @ W + bias via prepacked
// granule tiles. 64x64 tile, BK=64, 4 waves each 32x32.
// C = Ah*Wh + Ah*Wl + Al*Wh. XCD swizzle: bx = nb*64 + mp.
// Staged main loop (double-buffered global_load_lds, 1 barrier/kstep) —
// R13's direct-L2 variant regressed (+21 us, 2x L2 traffic); keep staged.
// FUSED EPILOGUES (EPI):
//   EPI 0: plain fp32 C write (out proj)
//   EPI 1: packed K tiles SCALED BY 1/8 + cbk dot (cb . k * 0.125 - 8)
//   EPI 2: packed V tiles (transposed V-frag layout)
//   EPI 3: packed R chunks SCALED BY 1/8 + rbrk dot (rb . relk * 0.125)
//   EPI 4: packed Q as A-granule tiles (Q proj; attn reads frags directly)
// R18: the attention 1/8 logit scale is folded into the K and R packs
// (power-of-2: split2(x/8) == split2(x)/8 EXACTLY). Q packed raw.
// ---------------------------------------------------------------------------
__device__ __forceinline__ void gemm_full(
    const u16* __restrict__ Apk, const u16* __restrict__ Wpk,
    const float* __restrict__ bias, float* __restrict__ C,
    u16* __restrict__ Ppk, const float* __restrict__ dotv,
    float* __restrict__ dotout, int EPI, int bx, int tid) {
    __shared__ __align__(16) u16 Stage[2][16384];   // [half][A0 A1 W0 W1]

    const int w = tid >> 6, lane = tid & 63, quad = lane >> 4, c = lane & 15;
    const int mp = bx & 63, nb = bx >> 6;
    const int mq = w >> 1, nq = w & 1;

    auto stage_async = [&](int kb, int half) {
        const u16* s = (w < 2)
            ? Apk + (size_t)((2 * mp + w) * 8 + kb) * 4096
            : Wpk + (size_t)((2 * nb + (w & 1)) * 8 + kb) * 4096;
        const u16* g = s + lane * 8;
        u16* d = Stage[half] + w * 4096;
#pragma unroll
        for (int u2 = 0; u2 < 8; u2++)
            load_lds16(g + u2 * 512, d + u2 * 512);
    };

    stage_async(0, 0);

    f32x4 acc[2][2];
#pragma unroll
    for (int mh = 0; mh < 2; mh++)
#pragma unroll
        for (int nh = 0; nh < 2; nh++) acc[mh][nh] = (f32x4){0.f, 0.f, 0.f, 0.f};

    for (int kb = 0; kb < 8; kb++) {
        const int half = kb & 1;
        __syncthreads();          // drains this half's DMA; prior reads done
        if (kb < 7) stage_async(kb + 1, 1 - half);
        const u16* Ab = Stage[half] + mq * 4096;
        const u16* Wb = Stage[half] + 8192 + nq * 4096;
#pragma unroll
        for (int s = 0; s < 2; s++) {
            bf16x8 ah[2], al[2], wh[2], wl[2];
#pragma unroll
            for (int t = 0; t < 2; t++) {
                int g = (t << 7) + (c << 3) + (((s << 2) + quad + 5 * c) & 7);
                ah[t] = *(const bf16x8*)(Ab + g * 8);
                al[t] = *(const bf16x8*)(Ab + 2048 + g * 8);
                wh[t] = *(const bf16x8*)(Wb + g * 8);
                wl[t] = *(const bf16x8*)(Wb + 2048 + g * 8);
            }
#pragma unroll
            for (int mh = 0; mh < 2; mh++)
#pragma unroll
                for (int nh = 0; nh < 2; nh++) {
                    acc[mh][nh] = __builtin_amdgcn_mfma_f32_16x16x32_bf16(
                        ah[mh], wh[nh], acc[mh][nh], 0, 0, 0);
                    acc[mh][nh] = __builtin_amdgcn_mfma_f32_16x16x32_bf16(
                        ah[mh], wl[nh], acc[mh][nh], 0, 0, 0);
                    acc[mh][nh] = __builtin_amdgcn_mfma_f32_16x16x32_bf16(
                        al[mh], wh[nh], acc[mh][nh], 0, 0, 0);
                }
        }
    }

    const int n0 = nb * 64 + nq * 32;
    float bv0 = bias ? bias[n0 + c] : 0.f;
    float bv1 = bias ? bias[n0 + 16 + c] : 0.f;

    if (EPI == 0) {
        const int m0 = mp * 64 + mq * 32;
#pragma unroll
        for (int mh = 0; mh < 2; mh++)
#pragma unroll
            for (int r = 0; r < 4; r++) {
                size_t row = (size_t)(m0 + mh * 16 + quad * 4 + r) * 512;
                C[row + n0 + c]      = acc[mh][0][r] + bv0;
                C[row + n0 + 16 + c] = acc[mh][1][r] + bv1;
            }
        return;
    }

    // ---- packing epilogues: C tile -> LDS fp32, then granule-pack ----
    __syncthreads();                               // all waves done w/ Stage
    float (*Cl)[68] = (float (*)[68])Stage;        // [64][68] = 17.4 KB
    {
        const int rbase = mq * 32;
#pragma unroll
        for (int mh = 0; mh < 2; mh++)
#pragma unroll
            for (int r = 0; r < 4; r++) {
                int row = rbase + mh * 16 + quad * 4 + r;
                Cl[row][nq * 32 + c]      = acc[mh][0][r] + bv0;
                Cl[row][nq * 32 + 16 + c] = acc[mh][1][r] + bv1;
            }
    }
    __syncthreads();

    if (EPI == 2) {                                // V tiles (transposed frag)
        const int b = mp >> 5, jt0 = (mp & 31) * 2;
        const int d = tid >> 2, kq = tid & 3;
        const int n = d & 15;
        const int g = (d >> 4) * 64 + n * 4 + ((kq + (n >> 1)) & 3);
#pragma unroll
        for (int ht = 0; ht < 2; ht++) {
            float xs[8];
#pragma unroll
            for (int e = 0; e < 8; e++) xs[e] = Cl[ht * 32 + kq * 8 + e][d];
            u16* dt = Ppk + (size_t)(b * 512 + nb * 64 + jt0 + ht) * 4096;
            pack_granule(xs, dt, g);
        }
        return;
    }

    // EPI 1 (K, x1/8) / EPI 3 (R, x1/8) / EPI 4 (Q, raw): B/A-frag granule
    {
        const float scl = (EPI == 4) ? 1.0f : 0.125f;
        const int rr = tid >> 3, f = tid & 7;
        const int s = f >> 2, kq = f & 3, nt = rr >> 4, n = rr & 15;
        const int g = nt * 128 + n * 8 + ((4 * s + kq + 5 * n) & 7);
#pragma unroll
        for (int ht = 0; ht < 2; ht++) {
            float xs[8];
#pragma unroll
            for (int e = 0; e < 8; e++) xs[e] = Cl[ht * 32 + rr][f * 8 + e] * scl;
            size_t tidx = (EPI == 1)
                ? (size_t)((mp >> 5) * 512 + nb * 64 + (mp & 31) * 2 + ht)
                : (EPI == 3)
                ? (size_t)(nb * 128 + mp * 2 + ht)
                : (size_t)((mp * 2 + ht) * 8 + nb);
            pack_granule(xs, Ppk + tidx * 4096, g);
        }
    }
    if (EPI != 4 && tid < 64) {                    // bias-fold dot, 1 row/lane
        const float* dv = dotv + nb * 64;
        const float* rowp = Cl[tid];
        float sacc = 0.f;
#pragma unroll
        for (int d = 0; d < 64; d++) sacc += dv[d] * rowp[d];
        int m = mp * 64 + tid;
        if (EPI == 1) {
            int b = m >> 11, t = m & 2047;
            dotout[((size_t)nb * BB + b) * TT + t] = sacc * 0.125f - 8.0f;
        } else {
            dotout[(size_t)nb * 4096 + m] = sacc * 0.125f;
        }
    }
}

__global__ __launch_bounds__(256, 2) void gemm_mfma_kernel(
    const u16* __restrict__ Apk, const u16* __restrict__ Wpk,
    const float* __restrict__ bias, float* __restrict__ C) {
    gemm_full(Apk, Wpk, bias, C, nullptr, nullptr, nullptr, 0,
              blockIdx.x, threadIdx.x);
}

// rel_k GEMM: pe-packed A x Wr -> packed R chunks (x1/8) + rbrk. Grid 512.
__global__ __launch_bounds__(256, 2) void gemm_relk_kernel(
    const u16* __restrict__ Apk, const u16* __restrict__ Wpk,
    const float* __restrict__ rb, u16* __restrict__ Rpk,
    float* __restrict__ rbrk) {
    gemm_full(Apk, Wpk, nullptr, nullptr, Rpk, rb, rbrk, 3,
              blockIdx.x, threadIdx.x);
}

// Fused Q/K/V projection GEMMs: grid 1536, widx = bx>>9.
// widx0 -> packed Q A-tiles (EPI4); widx1 -> packed K (x1/8) + cbk;
// widx2 -> packed V.
__global__ __launch_bounds__(256, 2) void gemm3_mfma_kernel(
    const u16* __restrict__ Aq, const u16* __restrict__ Ak,
    const u16* __restrict__ Av, const u16* __restrict__ Wpk,
    const float* __restrict__ bq, const float* __restrict__ bk,
    const float* __restrict__ bv, const float* __restrict__ cb,
    u16* __restrict__ Qpk, u16* __restrict__ Kpk, u16* __restrict__ Vpk,
    float* __restrict__ cbk) {
    const int widx = blockIdx.x >> 9, bx = blockIdx.x & 511;
    const u16* A = widx == 0 ? Aq : widx == 1 ? Ak : Av;
    const u16* W = Wpk + (size_t)widx * WSZ;
    const float* bias = widx == 0 ? bq : widx == 1 ? bk : bv;
    u16* P = widx == 0 ? Qpk : widx == 1 ? Kpk : Vpk;
    const int EPI = widx == 0 ? 4 : widx;
    gemm_full(A, W, bias, nullptr, P, widx == 1 ? cb : nullptr,
              widx == 1 ? cbk : nullptr, EPI, bx, threadIdx.x);
}

// ---------------------------------------------------------------------------
// MFMA flash attention with Transformer-XL rel-shift.
// R8-R18: no-max softmax (-8 shift in cbk), l = mfma(p, ones), KV-split
// 2-wave blocks, no in-loop barriers, 3-slot mod-3 ring, per-head XCD-L2
// affinity, 32 q-rows/wave, packed A-tile epilogue, V-load hoist, Q-direct
// from packed tiles, hi-only P via stride-40 Pbuf (one b128 read).
// R21 CHAIN SPLIT: the kernel is MFMA-LATENCY bound (46 MFMAs/tile ~ 6 us
// of pipe time vs 103 us wall; 2 waves/SIMD can't hide ~16-20 cyc MFMA
// latency inside 12-deep accumulator chains). QK and produce accumulators
// are split by the s-index into independent 3-deep chains (4 chains live
// per phase instead of 2x 12/6-deep), summed in the existing sv/ring adds.
// FP order changes in last bits only (margin to threshold is ~5x).
// ---------------------------------------------------------------------------
__global__ __launch_bounds__(128, 2) void attn_mfma_kernel(
    const u16* __restrict__ Qpk, const u16* __restrict__ Kpk,
    const u16* __restrict__ Vpk, const u16* __restrict__ Rpk,
    const float* __restrict__ cbk, const float* __restrict__ rbrk,
    u16* __restrict__ Aout) {
    __shared__ float Ring[2 * 3 * 1120];           // [wave][slot][32][35]
    __shared__ __align__(16) u16 Pbuf[2 * 1280];   // [wave][32 rows][40]

    const int tid = threadIdx.x;
    const int w = tid >> 6, lane = tid & 63, quad = lane >> 4, c = lane & 15;
    const int bx = blockIdx.x;
    const int h = bx & 7, b = (bx >> 3) & 1, it = bx >> 4;   // h in low bits
    const int i0 = it * 32;

    // Q fragments direct from packed A-tile: [rg][s]
    frag_u qh[2][2], ql[2][2];
    {
        const u16* Qt = Qpk + (size_t)((b * 64 + it) * 8 + h) * 4096;
#pragma unroll
        for (int rg = 0; rg < 2; rg++)
#pragma unroll
            for (int s = 0; s < 2; s++) {
                int g = (rg << 7) + (c << 3) + (((s << 2) + quad + 5 * c) & 7);
                qh[rg][s].f = *(const bf16x8*)(Qt + g * 8);
                ql[rg][s].f = *(const bf16x8*)(Qt + 2048 + g * 8);
            }
    }

    // all-ones B fragment for row-sum MFMAs (l accumulation)
    frag_u onesf;
#pragma unroll
    for (int j2 = 0; j2 < 8; j2++) onesf.u[j2] = 0x3f80u;   // bf16 1.0

    const u16* Ktiles  = Kpk + (size_t)(b * HH + h) * 64 * 4096;
    const u16* Vtiles  = Vpk + (size_t)(b * HH + h) * 64 * 4096;
    const u16* Rchunks = Rpk + (size_t)h * 128 * 4096;
    const float* rbrk_h = rbrk + (size_t)h * (2 * TT);
    const float* cbk_h  = cbk + ((size_t)h * BB + b) * TT;

    auto read_kr = [&](const u16* reg, int nt, int s, bf16x8& fh, bf16x8& fl) {
        int g = (nt << 7) + (c << 3) + (((s << 2) + quad + 5 * c) & 7);
        fh = *(const bf16x8*)(reg + g * 8);
        fl = *(const bf16x8*)(reg + 2048 + g * 8);
    };
    auto read_v = [&](const u16* Vb, int ntd, bf16x8& fh, bf16x8& fl) {
        int g = ntd * 64 + c * 4 + ((quad + (c >> 1)) & 3);
        fh = *(const bf16x8*)(Vb + g * 8);
        fl = *(const bf16x8*)(Vb + 2048 + g * 8);
    };

    // produce: Q(32 rows) . (R/8)-chunk -> ring slot [32][35]
    // R21: 4 independent 3-deep chains (split by s), summed at the write.
    auto produce = [&](int cidx) {
        const u16* Rc = Rchunks + (size_t)cidx * 4096;
        float* ringw = Ring + (w * 3 + cidx % 3) * 1120;
#pragma unroll
        for (int ntp = 0; ntp < 2; ntp++) {
            f32x4 a0s0 = {0.f, 0.f, 0.f, 0.f}, a0s1 = {0.f, 0.f, 0.f, 0.f};
            f32x4 a1s0 = {0.f, 0.f, 0.f, 0.f}, a1s1 = {0.f, 0.f, 0.f, 0.f};
            bf16x8 fh0, fl0, fh1, fl1;
            {
                int g0 = (ntp << 7) + (c << 3) + ((quad + 5 * c) & 7);
                int g1 = (ntp << 7) + (c << 3) + ((4 + quad + 5 * c) & 7);
                fh0 = *(const bf16x8*)(Rc + g0 * 8);
                fl0 = *(const bf16x8*)(Rc + 2048 + g0 * 8);
                fh1 = *(const bf16x8*)(Rc + g1 * 8);
                fl1 = *(const bf16x8*)(Rc + 2048 + g1 * 8);
            }
            a0s0 = __builtin_amdgcn_mfma_f32_16x16x32_bf16(qh[0][0].f, fh0, a0s0, 0, 0, 0);
            a0s0 = __builtin_amdgcn_mfma_f32_16x16x32_bf16(qh[0][0].f, fl0, a0s0, 0, 0, 0);
            a0s0 = __builtin_amdgcn_mfma_f32_16x16x32_bf16(ql[0][0].f, fh0, a0s0, 0, 0, 0);
            a0s1 = __builtin_amdgcn_mfma_f32_16x16x32_bf16(qh[0][1].f, fh1, a0s1, 0, 0, 0);
            a0s1 = __builtin_amdgcn_mfma_f32_16x16x32_bf16(qh[0][1].f, fl1, a0s1, 0, 0, 0);
            a0s1 = __builtin_amdgcn_mfma_f32_16x16x32_bf16(ql[0][1].f, fh1, a0s1, 0, 0, 0);
            a1s0 = __builtin_amdgcn_mfma_f32_16x16x32_bf16(qh[1][0].f, fh0, a1s0, 0, 0, 0);
            a1s0 = __builtin_amdgcn_mfma_f32_16x16x32_bf16(qh[1][0].f, fl0, a1s0, 0, 0, 0);
            a1s0 = __builtin_amdgcn_mfma_f32_16x16x32_bf16(ql[1][0].f, fh0, a1s0, 0, 0, 0);
            a1s1 = __builtin_amdgcn_mfma_f32_16x16x32_bf16(qh[1][1].f, fh1, a1s1, 0, 0, 0);
            a1s1 = __builtin_amdgcn_mfma_f32_16x16x32_bf16(qh[1][1].f, fl1, a1s1, 0, 0, 0);
            a1s1 = __builtin_amdgcn_mfma_f32_16x16x32_bf16(ql[1][1].f, fh1, a1s1, 0, 0, 0);
            float rbv = rbrk_h[cidx * 32 + ntp * 16 + c];
            int mpos = ntp * 16 + c;
#pragma unroll
            for (int r = 0; r < 4; r++)
                ringw[(quad * 4 + r) * 35 + mpos] = a0s0[r] + a0s1[r] + rbv;
#pragma unroll
            for (int r = 0; r < 4; r++)
                ringw[(16 + quad * 4 + r) * 35 + mpos] = a1s0[r] + a1s1[r] + rbv;
        }
    };

    // base m at (row i0, local j=0); aligned to 32 since i0,j0 = 0 mod 32.
    const int base = TT - i0 + 1024 * w;
    const int F = (base >> 5) - 1;      // first chunk of the t=0 window
    produce(F);
    produce(F + 1);

    f32x4 o[2][4];
    f32x4 acc_l[2];
#pragma unroll
    for (int rg = 0; rg < 2; rg++) {
        acc_l[rg] = (f32x4){0.f, 0.f, 0.f, 0.f};
#pragma unroll
        for (int nt = 0; nt < 4; nt++) o[rg][nt] = (f32x4){0.f, 0.f, 0.f, 0.f};
    }

    for (int t = 0; t < 32; t++) {
        const int j0 = 1024 * w + 32 * t;
        const u16* Kb = Ktiles + (size_t)(w * 32 + t) * 4096;
        const u16* Vb = Vtiles + (size_t)(w * 32 + t) * 4096;

        // V loads issued FIRST — consumed at PV (end of body), covered by
        // produce + QK + softmax in between (R17).
        bf16x8 vfh[4], vfl[4];
#pragma unroll
        for (int ntd = 0; ntd < 4; ntd++) read_v(Vb, ntd, vfh[ntd], vfl[ntd]);

        int cnext = F + t + 2;
        if (cnext < 128) produce(cnext);

        // window chunks {F+t, F+t+1}; slots mod 3
        const int slo = (F + t) % 3;
        const int shi = (slo == 2) ? 0 : slo + 1;
        const int off_lo = (w * 3 + slo) * 1120;
        const int off_hi = (w * 3 + shi) * 1120;
        float cbv0 = cbk_h[j0 + c];
        float cbv1 = cbk_h[j0 + 16 + c];
        float sv[2][2][4];
#pragma unroll
        for (int nt = 0; nt < 2; nt++) {
            // R21: 4 independent 3-deep QK chains (split by s)
            f32x4 p0s0 = {0.f, 0.f, 0.f, 0.f}, p0s1 = {0.f, 0.f, 0.f, 0.f};
            f32x4 p1s0 = {0.f, 0.f, 0.f, 0.f}, p1s1 = {0.f, 0.f, 0.f, 0.f};
            bf16x8 fh0, fl0, fh1, fl1;
            read_kr(Kb, nt, 0, fh0, fl0);
            read_kr(Kb, nt, 1, fh1, fl1);
            __builtin_amdgcn_s_setprio(1);
            p0s0 = __builtin_amdgcn_mfma_f32_16x16x32_bf16(qh[0][0].f, fh0, p0s0, 0, 0, 0);
            p0s0 = __builtin_amdgcn_mfma_f32_16x16x32_bf16(qh[0][0].f, fl0, p0s0, 0, 0, 0);
            p0s0 = __builtin_amdgcn_mfma_f32_16x16x32_bf16(ql[0][0].f, fh0, p0s0, 0, 0, 0);
            p0s1 = __builtin_amdgcn_mfma_f32_16x16x32_bf16(qh[0][1].f, fh1, p0s1, 0, 0, 0);
            p0s1 = __builtin_amdgcn_mfma_f32_16x16x32_bf16(qh[0][1].f, fl1, p0s1, 0, 0, 0);
            p0s1 = __builtin_amdgcn_mfma_f32_16x16x32_bf16(ql[0][1].f, fh1, p0s1, 0, 0, 0);
            p1s0 = __builtin_amdgcn_mfma_f32_16x16x32_bf16(qh[1][0].f, fh0, p1s0, 0, 0, 0);
            p1s0 = __builtin_amdgcn_mfma_f32_16x16x32_bf16(qh[1][0].f, fl0, p1s0, 0, 0, 0);
            p1s0 = __builtin_amdgcn_mfma_f32_16x16x32_bf16(ql[1][0].f, fh0, p1s0, 0, 0, 0);
            p1s1 = __builtin_amdgcn_mfma_f32_16x16x32_bf16(qh[1][1].f, fh1, p1s1, 0, 0, 0);
            p1s1 = __builtin_amdgcn_mfma_f32_16x16x32_bf16(qh[1][1].f, fl1, p1s1, 0, 0, 0);
            p1s1 = __builtin_amdgcn_mfma_f32_16x16x32_bf16(ql[1][1].f, fh1, p1s1, 0, 0, 0);
            __builtin_amdgcn_s_setprio(0);
            float cbv = nt ? cbv1 : cbv0;
#pragma unroll
            for (int r = 0; r < 4; r++) {
                int row16 = quad * 4 + r;
                int rel0 = nt * 16 + c - row16 + 32;
                float rv0 = Ring[((rel0 >= 32) ? off_hi : off_lo)
                                 + row16 * 35 + (rel0 & 31)];
                sv[0][nt][r] = p0s0[r] + p0s1[r] + rv0 + cbv;
                int rel1 = rel0 - 16;
                float rv1 = Ring[((rel1 >= 32) ? off_hi : off_lo)
                                 + (16 + row16) * 35 + (rel1 & 31)];
                sv[1][nt][r] = p1s0[r] + p1s1[r] + rv1 + cbv;
            }
        }

        // p~ = bf16(exp(s - 8)); weights sum to exactly 1 via l = sum(p~).
#pragma unroll
        for (int rg = 0; rg < 2; rg++)
#pragma unroll
            for (int r = 0; r < 4; r++) {
                u16* pb = Pbuf + w * 1280 + (16 * rg + quad * 4 + r) * 40;
                pb[c]      = bf16_rne(__expf(sv[rg][0][r]));
                pb[16 + c] = bf16_rne(__expf(sv[rg][1][r]));
            }

        frag_u ph[2];
#pragma unroll
        for (int rg = 0; rg < 2; rg++) {
            // row-major [row][j] u16 layout == PV A-frag: one b128 read.
            const u16* pb = Pbuf + w * 1280 + (16 * rg + c) * 40 + quad * 8;
            *(uint4*)&ph[rg] = *(const uint4*)pb;
        }
        __builtin_amdgcn_s_setprio(1);
#pragma unroll
        for (int ntd = 0; ntd < 4; ntd++) {
            o[0][ntd] = __builtin_amdgcn_mfma_f32_16x16x32_bf16(ph[0].f, vfh[ntd], o[0][ntd], 0, 0, 0);
            o[0][ntd] = __builtin_amdgcn_mfma_f32_16x16x32_bf16(ph[0].f, vfl[ntd], o[0][ntd], 0, 0, 0);
            o[1][ntd] = __builtin_amdgcn_mfma_f32_16x16x32_bf16(ph[1].f, vfh[ntd], o[1][ntd], 0, 0, 0);
            o[1][ntd] = __builtin_amdgcn_mfma_f32_16x16x32_bf16(ph[1].f, vfl[ntd], o[1][ntd], 0, 0, 0);
        }
        // l accumulation: every column of mfma(p, ones) holds sum_j p[row,j].
        acc_l[0] = __builtin_amdgcn_mfma_f32_16x16x32_bf16(ph[0].f, onesf.f, acc_l[0], 0, 0, 0);
        acc_l[1] = __builtin_amdgcn_mfma_f32_16x16x32_bf16(ph[1].f, onesf.f, acc_l[1], 0, 0, 0);
        __builtin_amdgcn_s_setprio(0);
    }

    // Combine the two KV-half partials: pure sums (no max tracking).
    // Wave 1 parks (o, l) inside ITS OWN ring half (Ring+3360) — disjoint
    // from wave 0's live slots and dead for wave 1 here.
    float* scr = Ring + 3360;      // [32 rows][65] + l at [2080 + row]
    if (w == 1) {
#pragma unroll
        for (int rg = 0; rg < 2; rg++) {
#pragma unroll
            for (int nt = 0; nt < 4; nt++)
#pragma unroll
                for (int r = 0; r < 4; r++)
                    scr[(16 * rg + quad * 4 + r) * 65 + nt * 16 + c] = o[rg][nt][r];
            if (c == 0) {
#pragma unroll
                for (int r = 0; r < 4; r++)
                    scr[2080 + 16 * rg + quad * 4 + r] = acc_l[rg][r];
            }
        }
    }
    __syncthreads();
    // Wave 0 combines and writes finals to LDS (its own dead ring half),
    // then both waves granule-pack the 32x64 tile into the out-proj A-tile.
    float* Lp = Ring;              // [32][68] = 8.7 KB inside wave-0 ring
    if (w == 0) {
#pragma unroll
        for (int rg = 0; rg < 2; rg++)
#pragma unroll
            for (int r = 0; r < 4; r++) {
                int row16 = quad * 4 + r;
                int row32 = 16 * rg + row16;
                float invl = 1.0f / (acc_l[rg][r] + scr[2080 + row32]);
#pragma unroll
                for (int nt = 0; nt < 4; nt++)
                    Lp[row32 * 68 + nt * 16 + c] =
                        (o[rg][nt][r] + scr[row32 * 65 + nt * 16 + c]) * invl;
            }
    }
    __syncthreads();
    u16* dt = Aout + (size_t)((b * 64 + it) * 8 + h) * 4096;
#pragma unroll
    for (int pass = 0; pass < 2; pass++) {
        int idx = pass * 128 + tid;
        int rr = idx >> 3, f = idx & 7;
        float xs[8];
#pragma unroll
        for (int e = 0; e < 8; e++) xs[e] = Lp[rr * 68 + f * 8 + e];
        int s = f >> 2, kq = f & 3, nt2 = rr >> 4, n = rr & 15;
        int g = nt2 * 128 + n * 8 + ((4 * s + kq + 5 * n) & 7);
        pack_granule(xs, dt, g);
    }
}

// ---------------------------------------------------------------------------
extern "C" void kernel_launch(void* const* d_in, const int* in_sizes, int n_in,
                              void* d_out, int out_size, void* d_ws, size_t ws_size,
                              hipStream_t stream) {
    const float* query  = (const float*)d_in[0];
    const float* key_in = (const float*)d_in[1];
    const float* value  = (const float*)d_in[2];
    const float* Wq = (const float*)d_in[3];
    const float* bq = (const float*)d_in[4];
    const float* Wk = (const float*)d_in[5];
    const float* bk = (const float*)d_in[6];
    const float* Wv = (const float*)d_in[7];
    const float* bv = (const float*)d_in[8];
    const float* Wr = (const float*)d_in[9];
    const float* cb = (const float*)d_in[10];
    const float* rb = (const float*)d_in[11];
    const float* Wo = (const float*)d_in[12];
    const float* bo = (const float*)d_in[13];
    float* out = (float*)d_out;

    float* ws = (float*)d_ws;
    const size_t SL = (size_t)MM * DD;        // 2097152 floats (8 MB) per slot
    // Slot map (R18): s0 PePk -> Qpk | s1 Kpk | s2 Vpk | s3 Rpk
    //   s4 Apk_v -> Apk_o | s5 Apk_k | s6 Apk_q
    //   s7 Wpk (5 MB) + cbk + rbrk
    u16*   PePk = (u16*)ws;
    u16*   Qpk  = (u16*)ws;
    u16*   Kpk  = (u16*)(ws + 1 * SL);
    u16*   Vpk  = (u16*)(ws + 2 * SL);
    u16*   Rpk  = (u16*)(ws + 3 * SL);
    u16*   s4   = (u16*)(ws + 4 * SL);
    u16*   s5   = (u16*)(ws + 5 * SL);
    u16*   s6   = (u16*)(ws + 6 * SL);
    u16*   Wpk  = (u16*)(ws + 7 * SL);
    float* cbk  = ws + 7 * SL + 1310720;      // [H*B*T]
    float* rbrk = cbk + BB * TT * HH;         // [H*2T]

    // ONE launch for every prepack (weights, pe, Q/K/V A-operands)
    prepack_all_kernel<<<4736, 256, 0, stream>>>(
        Wq, Wk, Wv, Wr, Wo, Wpk, PePk,
        query, key_in, value, s6, s5, s4);

    // rel_k GEMM -> packed R (x1/8) + rbrk (reads pe in s0; frees s0)
    gemm_relk_kernel<<<512, 256, 0, stream>>>(PePk, Wpk + 3 * WSZ, rb, Rpk, rbrk);

    // fused Q/K/V projection GEMMs (Q packed raw, K packed x1/8 + cbk, V)
    gemm3_mfma_kernel<<<1536, 256, 0, stream>>>(s6, s5, s4, Wpk, bq, bk, bv,
                                                cb, Qpk, Kpk, Vpk, cbk);

    // attention -> packed out-proj A operand directly (s4 reuse)
    attn_mfma_kernel<<<BB * HH * (TT / 32), 128, 0, stream>>>(
        Qpk, Kpk, Vpk, Rpk, cbk, rbrk, s4);

    // output projection
    gemm_mfma_kernel<<<512, 256, 0, stream>>>(s4, Wpk + 4 * WSZ, bo, out);
}